// Round 1
// baseline (7055.277 us; speedup 1.0000x reference)
//
#include <hip/hip_runtime.h>
#include <stdint.h>

// Model dims
#define D_   1024
#define T_   512
#define B_   8
#define V_   8
#define I_   1032
#define KP_  1088   // padded K for token_feats GEMM (17*64)
#define TDK  3072

typedef __attribute__((ext_vector_type(8))) short bf16x8;
typedef __attribute__((ext_vector_type(4))) float f32x4;

__device__ __forceinline__ ushort f2bf(float f){
  union{ unsigned u; float f; } c; c.f = f;
  unsigned u = c.u;
  return (ushort)((u + 0x7FFFu + ((u>>16)&1u)) >> 16);   // RNE
}
__device__ __forceinline__ float sigmoidf_(float x){ return 1.f/(1.f+__expf(-x)); }

// ---------------- prep: x*mask -> f32 + bf16 ----------------
__global__ __launch_bounds__(256) void k_prep(const float* __restrict__ x, const float* __restrict__ mask,
                                              float* __restrict__ xm, ushort* __restrict__ xmb){
  int i = blockIdx.x*256 + threadIdx.x;          // float4 index, total 1048576
  float4 v = ((const float4*)x)[i];
  float mk = mask[i >> 8];                        // token = i*4/1024
  v.x*=mk; v.y*=mk; v.z*=mk; v.w*=mk;
  ((float4*)xm)[i] = v;
  ushort4 h; h.x=f2bf(v.x); h.y=f2bf(v.y); h.z=f2bf(v.z); h.w=f2bf(v.w);
  ((ushort4*)xmb)[i] = h;
}

// ---------------- generic f32 -> bf16 convert ----------------
__global__ __launch_bounds__(256) void k_cvt(const float* __restrict__ in, ushort* __restrict__ out, int n4){
  int i = blockIdx.x*256 + threadIdx.x;
  if (i < n4){
    float4 v = ((const float4*)in)[i];
    ushort4 h; h.x=f2bf(v.x); h.y=f2bf(v.y); h.z=f2bf(v.z); h.w=f2bf(v.w);
    ((ushort4*)out)[i] = h;
  }
}

// op_W1 (8,1024,1032) f32 -> (8,1024,1088) bf16 zero-padded
__global__ __launch_bounds__(256) void k_cvt_w1(const float* __restrict__ w1, ushort* __restrict__ w1b){
  int row = blockIdx.x;                           // 8192 rows
  const float* src = w1 + (size_t)row*I_;
  ushort* dst = w1b + (size_t)row*KP_;
  for (int c = threadIdx.x; c < KP_; c += 256){
    float v = (c < I_) ? src[c] : 0.f;
    dst[c] = f2bf(v);
  }
}

// ---------------- bf16 MFMA GEMM: C(M,N) = A(M,K) @ B(N,K)^T, 128x128 tile ----------------
struct EpiArgs {
  float* outf; ushort* outh;
  const float* bias; const float* wvp; const float* obias;
  int v; int ldc;
};

template<int EPI, bool INIT>
__global__ __launch_bounds__(256) void k_gemm(const ushort* __restrict__ A, const ushort* __restrict__ Bm,
                                              int lda, int ldb, int K, EpiArgs e)
{
  __shared__ ushort As[128][72];   // +8 pad: 2-way-max bank aliasing on b128 reads
  __shared__ ushort Bs[128][72];
  const int tid = threadIdx.x;
  const int w = tid >> 6, l = tid & 63;
  const int wr = w >> 1, wc = w & 1;
  f32x4 acc[4][4] = {};
  const int srow = tid >> 1, shalf = tid & 1;
  const ushort* Ag = A  + (size_t)(blockIdx.x*128 + srow)*lda + shalf*32;
  const ushort* Bg = Bm + (size_t)(blockIdx.y*128 + srow)*ldb + shalf*32;
  ushort* Aw = &As[srow][shalf*32];
  ushort* Bw = &Bs[srow][shalf*32];
  for (int k0 = 0; k0 < K; k0 += 64){
    uint4 a0 = *(const uint4*)(Ag + k0);
    uint4 a1 = *(const uint4*)(Ag + k0 + 8);
    uint4 a2 = *(const uint4*)(Ag + k0 + 16);
    uint4 a3 = *(const uint4*)(Ag + k0 + 24);
    uint4 b0 = *(const uint4*)(Bg + k0);
    uint4 b1 = *(const uint4*)(Bg + k0 + 8);
    uint4 b2 = *(const uint4*)(Bg + k0 + 16);
    uint4 b3 = *(const uint4*)(Bg + k0 + 24);
    __syncthreads();
    *(uint4*)(Aw) = a0; *(uint4*)(Aw+8) = a1; *(uint4*)(Aw+16) = a2; *(uint4*)(Aw+24) = a3;
    *(uint4*)(Bw) = b0; *(uint4*)(Bw+8) = b1; *(uint4*)(Bw+16) = b2; *(uint4*)(Bw+24) = b3;
    __syncthreads();
    #pragma unroll
    for (int kk = 0; kk < 2; ++kk){
      bf16x8 af[4], bfr[4];
      #pragma unroll
      for (int m=0;m<4;++m) af[m]  = *(const bf16x8*)&As[wr*64 + m*16 + (l&15)][kk*32 + ((l>>4)<<3)];
      #pragma unroll
      for (int n=0;n<4;++n) bfr[n] = *(const bf16x8*)&Bs[wc*64 + n*16 + (l&15)][kk*32 + ((l>>4)<<3)];
      #pragma unroll
      for (int m=0;m<4;++m)
        #pragma unroll
        for (int n=0;n<4;++n)
          acc[m][n] = __builtin_amdgcn_mfma_f32_16x16x32_bf16(af[m], bfr[n], acc[m][n], 0, 0, 0);
    }
  }
  // C/D layout (m89): col = lane&15, row = (lane>>4)*4 + reg
  const int row0 = blockIdx.x*128 + wr*64 + ((l>>4)<<2);
  const int col0 = blockIdx.y*128 + wc*64 + (l&15);
  #pragma unroll
  for (int m=0;m<4;++m){
    #pragma unroll
    for (int n=0;n<4;++n){
      f32x4 a = acc[m][n];
      int col = col0 + n*16;
      #pragma unroll
      for (int q=0;q<4;++q){
        int row = row0 + m*16 + q;
        float val = a[q];
        if constexpr (EPI==0){                 // gx: + per-col bias (enc_bih), f32 out
          e.outf[(size_t)row*e.ldc + col] = val + e.bias[col];
        } else if constexpr (EPI==1){          // h1: gelu(acc+b1)*w[b,v] -> bf16
          float xg = val + e.bias[col];
          float g = 0.5f*xg*(1.0f + erff(xg*0.70710678118f));
          e.outh[(size_t)row*e.ldc + col] = f2bf(g * e.wvp[(row>>9)*V_ + e.v]);
        } else {                               // out accumulate across v
          size_t idx = (size_t)row*e.ldc + col;
          float prev = INIT ? e.obias[((row>>9)<<10) + col] : e.outf[idx];
          e.outf[idx] = prev + val;
        }
      }
    }
  }
}

// ---------------- persistent GRU recurrence: 64 WGs, grid barrier per step ----------------
// WG c owns dims [16c,16c+16); rows {d, D+d, 2D+d} so gate math is local.
// LDS: Wl[3][16][1024] bf16 (96KB) + Al[16][1032] bf16 (33KB, rows 8..15 = zero pad for M=16 MFMA)
//      + Red[4][3][128] f32 (6KB)  => 137472 B dynamic
__global__ __launch_bounds__(256) void k_gru(const float* __restrict__ whh, const float* __restrict__ bhh,
                                             const float* __restrict__ gx, float* __restrict__ hb,
                                             int* __restrict__ bar)
{
  extern __shared__ char smem[];
  ushort* Wl = (ushort*)smem;                       // [3][16][1024]
  ushort* Al = Wl + 3*16*1024;                      // [16][1032]
  float*  Red = (float*)(Al + 16*1032);             // [4][3][128]
  const int tid = threadIdx.x, c = blockIdx.x;
  const int w = tid >> 6, l = tid & 63;

  // zero Al (covers the 8 zero rows + pad; real rows rewritten each step)
  for (int u = tid; u < 16*1032/4; u += 256) ((unsigned long long*)Al)[u] = 0ULL;
  // stage W slice (f32 -> bf16)
  {
    const float4* wsrc = (const float4*)whh;
    for (int f = tid; f < 48*256; f += 256){
      int rl = f >> 8;                 // 0..47
      int g = rl >> 4, i = rl & 15;
      int kq = f & 255;
      float4 v = wsrc[((size_t)((g<<10) + (c<<4) + i))*256 + kq];
      ushort4 hh; hh.x=f2bf(v.x); hh.y=f2bf(v.y); hh.z=f2bf(v.z); hh.w=f2bf(v.w);
      *(ushort4*)(Wl + (g*16+i)*1024 + kq*4) = hh;
    }
  }
  __syncthreads();
  // hoist B fragments (constant across steps): wave w covers K quarter [w*256, w*256+256)
  bf16x8 Bf[3][8];
  {
    const int bi = l & 15, kg = (l>>4)<<3;
    #pragma unroll
    for (int g=0; g<3; ++g)
      #pragma unroll
      for (int s=0; s<8; ++s)
        Bf[g][s] = *(const bf16x8*)(Wl + (g*16 + bi)*1024 + w*256 + s*32 + kg);
  }
  const int dg0 = (c<<4) + (tid & 15);
  const float bhr = bhh[dg0], bhz = bhh[1024+dg0], bhn = bhh[2048+dg0];

  for (int t = 0; t < 512; ++t){
    if (t > 0){  // stage h_{t-1} (f32 global -> bf16 LDS rows 0..7)
      const float4* hs = (const float4*)(hb + (size_t)t*8192);
      #pragma unroll
      for (int ii=0; ii<8; ++ii){
        int f = tid + ii*256;
        float4 v = hs[f];
        ushort4 hv; hv.x=f2bf(v.x); hv.y=f2bf(v.y); hv.z=f2bf(v.z); hv.w=f2bf(v.w);
        *(ushort4*)(Al + (f>>8)*1032 + (f&255)*4) = hv;
      }
    }
    __syncthreads();
    f32x4 ac0={0.f,0.f,0.f,0.f}, ac1={0.f,0.f,0.f,0.f}, ac2={0.f,0.f,0.f,0.f};
    {
      const int ar = l & 15, kg = (l>>4)<<3;
      #pragma unroll
      for (int s=0;s<8;++s){
        bf16x8 af = *(const bf16x8*)(Al + ar*1032 + w*256 + s*32 + kg);
        ac0 = __builtin_amdgcn_mfma_f32_16x16x32_bf16(af, Bf[0][s], ac0, 0,0,0);
        ac1 = __builtin_amdgcn_mfma_f32_16x16x32_bf16(af, Bf[1][s], ac1, 0,0,0);
        ac2 = __builtin_amdgcn_mfma_f32_16x16x32_bf16(af, Bf[2][s], ac2, 0,0,0);
      }
    }
    if (l < 32){   // only rows m<8 are real (batch)
      *(f32x4*)(Red + (w*3+0)*128 + l*4) = ac0;
      *(f32x4*)(Red + (w*3+1)*128 + l*4) = ac1;
      *(f32x4*)(Red + (w*3+2)*128 + l*4) = ac2;
    }
    __syncthreads();
    if (tid < 128){
      const int b = tid >> 4, i = tid & 15;
      const int idx = (((b>>2)<<4) | i)*4 + (b & 3);   // D elem (m=b, n=i)
      float ghr = Red[idx]     + Red[384+idx]  + Red[768+idx]  + Red[1152+idx];
      float ghz = Red[128+idx] + Red[512+idx]  + Red[896+idx]  + Red[1280+idx];
      float ghn = Red[256+idx] + Red[640+idx]  + Red[1024+idx] + Red[1408+idx];
      const int dg = (c<<4) + i;
      size_t gb = ((size_t)(b*T_ + t))*TDK + dg;
      float xr = gx[gb], xz = gx[gb + 1024], xn = gx[gb + 2048];
      float hp = (t==0) ? 0.f : hb[(size_t)t*8192 + (b<<10) + dg];
      float r  = sigmoidf_(xr + ghr + bhr);
      float z  = sigmoidf_(xz + ghz + bhz);
      float nn = tanhf(xn + r*(ghn + bhn));
      hb[(size_t)(t+1)*8192 + (b<<10) + dg] = (1.f - z)*nn + z*hp;  // f32 carry
    }
    __threadfence();
    __syncthreads();
    if (tid == 0){
      __hip_atomic_fetch_add(bar, 1, __ATOMIC_RELEASE, __HIP_MEMORY_SCOPE_AGENT);
      const int target = 64*(t+1);
      while (__hip_atomic_load(bar, __ATOMIC_RELAXED, __HIP_MEMORY_SCOPE_AGENT) < target)
        __builtin_amdgcn_s_sleep(2);
    }
    __syncthreads();
    __threadfence();
  }
}

// ---------------- token feats: xe = gru+xm ; tt/pol heads ; build padded bf16 token_feats ----------------
__global__ __launch_bounds__(256) void k_tokfeat(const float* __restrict__ hb, const float* __restrict__ xm,
                                                 const float* __restrict__ ttW, const float* __restrict__ ttb,
                                                 const float* __restrict__ polW, const float* __restrict__ polb,
                                                 ushort* __restrict__ tf, float* __restrict__ ttpol){
  __shared__ float xe[1024];
  const int tok = blockIdx.x;              // b*512 + t
  const int b = tok >> 9, t = tok & 511;
  const int tid = threadIdx.x;
  float4 hv = ((const float4*)(hb + (size_t)(t+1)*8192 + ((size_t)b<<10)))[tid];
  float4 xv = ((const float4*)(xm + (size_t)tok*1024))[tid];
  float4 ev; ev.x=hv.x+xv.x; ev.y=hv.y+xv.y; ev.z=hv.z+xv.z; ev.w=hv.w+xv.w;
  *(float4*)&xe[tid*4] = ev;
  ushort4 eb; eb.x=f2bf(ev.x); eb.y=f2bf(ev.y); eb.z=f2bf(ev.z); eb.w=f2bf(ev.w);
  *(ushort4*)&tf[(size_t)tok*KP_ + tid*4] = eb;
  __syncthreads();
  const int j = tid >> 5, ln = tid & 31;
  const float* Wr = (j < 6) ? (ttW + j*1024) : (polW + (j-6)*1024);
  float acc = 0.f;
  for (int k = ln; k < 1024; k += 32) acc += xe[k]*Wr[k];
  #pragma unroll
  for (int m=16; m>=1; m>>=1) acc += __shfl_xor(acc, m, 32);
  if (ln == 0){
    float val = acc + ((j<6)? ttb[j] : polb[j-6]);
    ttpol[(size_t)tok*8 + j] = val;
    tf[(size_t)tok*KP_ + 1024 + j] = f2bf(val);
  }
  if (tid < 56) tf[(size_t)tok*KP_ + 1032 + tid] = 0;   // K padding
}

// pooled[b][d] = mean_t xe
__global__ __launch_bounds__(128) void k_pooled(const float* __restrict__ hb, const float* __restrict__ xm,
                                                float* __restrict__ pooled){
  const int b = blockIdx.x >> 3;
  const int d = ((blockIdx.x & 7) << 7) + threadIdx.x;
  float s = 0.f;
  for (int t=0; t<512; ++t)
    s += hb[(size_t)(t+1)*8192 + (b<<10) + d] + xm[((size_t)(b*512+t)<<10) + d];
  pooled[(b<<10)+d] = s * (1.f/512.f);
}

__global__ __launch_bounds__(64) void k_csum(const float* __restrict__ ttpol, float* __restrict__ csum){
  const int b = threadIdx.x >> 3, j = threadIdx.x & 7;
  float s = 0.f;
  for (int t=0; t<512; ++t) s += ttpol[((size_t)(b*512+t)<<3) + j];
  csum[threadIdx.x] = s * (1.f/512.f);
}

// pg_h0 = context @ c2h_W^T + c2h_b
__global__ __launch_bounds__(256) void k_ctx(const float* __restrict__ pooled, const float* __restrict__ csum,
                                             const float* __restrict__ c2hW, const float* __restrict__ c2hb,
                                             float* __restrict__ pgh0){
  const int i = blockIdx.x*256 + threadIdx.x;   // 8192
  const int b = i >> 10, d = i & 1023;
  const float* wr = c2hW + (size_t)d*I_;
  const float* pb = pooled + (b<<10);
  float acc = c2hb[d];
  for (int k=0; k<1024; ++k) acc += pb[k]*wr[k];
  #pragma unroll
  for (int k=0; k<8; ++k) acc += csum[b*8+k]*wr[1024+k];
  pgh0[i] = acc;
}

// one PG GRU step (rnn_in = 0 so gx = pg_bih)
__global__ __launch_bounds__(256) void k_pg(const float* __restrict__ whh, const float* __restrict__ bih,
                                            const float* __restrict__ bhh, const float* __restrict__ hin,
                                            float* __restrict__ hout){
  __shared__ float sh[8][1024];
  const int tid = threadIdx.x;
  for (int f = tid; f < 2048; f += 256) ((float4*)&sh[0][0])[f] = ((const float4*)hin)[f];
  __syncthreads();
  const int d = blockIdx.x*8 + (tid>>5), ln = tid & 31;
  const float* wr = whh + (size_t)d*1024;
  const float* wz = whh + (size_t)(1024+d)*1024;
  const float* wn = whh + (size_t)(2048+d)*1024;
  float ar[8]={0,0,0,0,0,0,0,0}, az[8]={0,0,0,0,0,0,0,0}, an[8]={0,0,0,0,0,0,0,0};
  for (int k = ln; k < 1024; k += 32){
    float r_=wr[k], z_=wz[k], n_=wn[k];
    #pragma unroll
    for (int b=0;b<8;++b){ float h = sh[b][k]; ar[b]+=h*r_; az[b]+=h*z_; an[b]+=h*n_; }
  }
  #pragma unroll
  for (int m=16; m>=1; m>>=1){
    #pragma unroll
    for (int b=0;b<8;++b){ ar[b]+=__shfl_xor(ar[b],m,32); az[b]+=__shfl_xor(az[b],m,32); an[b]+=__shfl_xor(an[b],m,32); }
  }
  if (ln == 0){
    float xr=bih[d], xz=bih[1024+d], xn=bih[2048+d];
    float br=bhh[d], bz=bhh[1024+d], bn=bhh[2048+d];
    #pragma unroll
    for (int b=0;b<8;++b){
      float r = sigmoidf_(xr + ar[b] + br);
      float z = sigmoidf_(xz + az[b] + bz);
      float nn = tanhf(xn + r*(an[b] + bn));
      hout[(b<<10)+d] = (1.f - z)*nn + z*sh[b][d];
    }
  }
}

// program logits + softmax + mean over L -> w[b][v]
__global__ __launch_bounds__(256) void k_wlogits(const float* __restrict__ pgh, const float* __restrict__ prjW,
                                                 const float* __restrict__ prjb, float* __restrict__ plog,
                                                 float* __restrict__ wv){
  __shared__ float lg[256];
  __shared__ float sm[256];
  const int tid = threadIdx.x;
  const int b = tid>>5, li = (tid>>3)&3, v = tid&7;
  const float* h = pgh + (size_t)(li+1)*8192 + (b<<10);
  const float* pw = prjW + (v<<10);
  float acc = prjb[v];
  for (int k=0;k<1024;++k) acc += h[k]*pw[k];
  lg[tid] = acc;         // tid == b*32 + li*8 + v
  plog[tid] = acc;
  __syncthreads();
  if (tid < 32){
    const int bb = tid>>2, ll = tid&3;
    const float* row = &lg[bb*32 + ll*8];
    float mx = row[0];
    #pragma unroll
    for (int u=1;u<8;++u) mx = fmaxf(mx, row[u]);
    float e[8], s=0.f;
    #pragma unroll
    for (int u=0;u<8;++u){ e[u]=__expf(row[u]-mx); s+=e[u]; }
    #pragma unroll
    for (int u=0;u<8;++u) sm[(bb*4+ll)*8+u] = e[u]/s;
  }
  __syncthreads();
  if (tid < 64){
    const int bb = tid>>3, u = tid&7;
    float s = sm[(bb*4+0)*8+u] + sm[(bb*4+1)*8+u] + sm[(bb*4+2)*8+u] + sm[(bb*4+3)*8+u];
    wv[bb*8+u] = 0.25f*s;
  }
}

__global__ __launch_bounds__(256) void k_obias(const float* __restrict__ wv, const float* __restrict__ opb2,
                                               float* __restrict__ obias){
  const int i = blockIdx.x*256 + threadIdx.x;   // 8192
  const int b = i>>10, d = i&1023;
  float s = 0.f;
  #pragma unroll
  for (int v=0; v<8; ++v) s += wv[b*8+v]*opb2[(v<<10)+d];
  obias[i] = s;
}

// pooled2 = [max_t out | mean_t out]
__global__ __launch_bounds__(128) void k_pool2(const float* __restrict__ outb, float* __restrict__ pooled2){
  const int b = blockIdx.x >> 3;
  const int col = ((blockIdx.x & 7) << 7) + threadIdx.x;
  float mx = -3.4e38f, sm = 0.f;
  for (int t=0; t<512; ++t){
    float v = outb[((size_t)(b*512+t)<<10) + col];
    mx = fmaxf(mx, v); sm += v;
  }
  pooled2[((size_t)b<<11) + col] = mx;
  pooled2[((size_t)b<<11) + 1024 + col] = sm*(1.f/512.f);
}

// z = pooled2 @ out_W^T + out_b  -> d_out[0..8191]
__global__ __launch_bounds__(256) void k_z(const float* __restrict__ pooled2, const float* __restrict__ outW,
                                           const float* __restrict__ outBias, float* __restrict__ dout){
  __shared__ float p2[2048];
  const int o = blockIdx.x << 3;
  const int b = o >> 10, dbase = o & 1023;
  for (int f = threadIdx.x; f < 512; f += 256)
    ((float4*)p2)[f] = ((const float4*)(pooled2 + ((size_t)b<<11)))[f];
  __syncthreads();
  const int g = threadIdx.x >> 5, ln = threadIdx.x & 31;
  const int d = dbase + g;
  const float* wr = outW + ((size_t)d << 11);
  float acc = 0.f;
  for (int k = ln; k < 2048; k += 32) acc += p2[k]*wr[k];
  #pragma unroll
  for (int m=16; m>=1; m>>=1) acc += __shfl_xor(acc, m, 32);
  if (ln == 0) dout[(b<<10) + d] = acc + outBias[d];
}

// reuse + contrastive losses (exact f32)
__global__ __launch_bounds__(64) void k_losses(const float* __restrict__ p2g, const float* __restrict__ plog,
                                               float* __restrict__ dout){
  __shared__ float p2n[8], sq[8], pn[8];
  const int l = threadIdx.x;
  { const int b=l>>3, p=l&7; float s=0.f;
    const float* row = p2g + ((size_t)b<<11) + (p<<8);
    for (int k=0;k<256;++k){ float v=row[k]; s += v*v; }
    s += __shfl_xor(s,4,8); s += __shfl_xor(s,2,8); s += __shfl_xor(s,1,8);
    if (p==0) p2n[b] = fmaxf(sqrtf(s), 1e-12f);
  }
  if (l < 8){
    float s=0.f;
    #pragma unroll
    for (int k=0;k<32;++k){ float v=plog[l*32+k]; s+=v*v; }
    sq[l]=s; pn[l]=fmaxf(sqrtf(s),1e-12f);
  }
  __syncthreads();
  const int i=l>>3, j=l&7;
  const float* ri = p2g + ((size_t)i<<11);
  const float* rj = p2g + ((size_t)j<<11);
  float dot=0.f; for (int k=0;k<2048;++k) dot += ri[k]*rj[k];
  float sim = dot/(p2n[i]*p2n[j]);
  float pd=0.f;
  #pragma unroll
  for (int k=0;k<32;++k) pd += plog[i*32+k]*plog[j*32+k];
  float d2 = fmaxf(sq[i]+sq[j]-2.f*pd, 0.f);
  float dist = (d2>0.f)? sqrtf(d2) : 0.f;
  float psim = pd/(pn[i]*pn[j]);
  float pos = (sim>0.7f)?1.f:0.f, neg = (sim<0.7f)?1.f:0.f;
  float rs = sim*dist, ps=(1.f-psim)*pos, ns=fmaxf(psim-0.5f,0.f)*neg, pc=pos, nc=neg;
  #pragma unroll
  for (int m=32; m>=1; m>>=1){
    rs+=__shfl_xor(rs,m); ps+=__shfl_xor(ps,m); ns+=__shfl_xor(ns,m);
    pc+=__shfl_xor(pc,m); nc+=__shfl_xor(nc,m);
  }
  if (l==0){ dout[8192]=rs*(1.f/64.f); dout[8193]=(ps+ns)/(pc+nc+1e-6f); }
}

// ============================ host ============================
extern "C" void kernel_launch(void* const* d_in, const int* in_sizes, int n_in,
                              void* d_out, int out_size, void* d_ws, size_t ws_size,
                              hipStream_t stream) {
  (void)in_sizes; (void)n_in; (void)out_size; (void)ws_size;
  const float* x     = (const float*)d_in[0];
  const float* amask = (const float*)d_in[1];
  const float* eWih  = (const float*)d_in[2];
  const float* eWhh  = (const float*)d_in[3];
  const float* ebih  = (const float*)d_in[4];
  const float* ebhh  = (const float*)d_in[5];
  const float* ttW   = (const float*)d_in[6];
  const float* ttb   = (const float*)d_in[7];
  const float* polW  = (const float*)d_in[8];
  const float* polb  = (const float*)d_in[9];
  const float* c2hW  = (const float*)d_in[10];
  const float* c2hb  = (const float*)d_in[11];
  const float* pgWhh = (const float*)d_in[13];
  const float* pgbih = (const float*)d_in[14];
  const float* pgbhh = (const float*)d_in[15];
  const float* prjW  = (const float*)d_in[16];
  const float* prjb  = (const float*)d_in[17];
  const float* opW1  = (const float*)d_in[18];
  const float* opb1  = (const float*)d_in[19];
  const float* opW2  = (const float*)d_in[20];
  const float* opb2  = (const float*)d_in[21];
  const float* outW  = (const float*)d_in[22];
  const float* outB  = (const float*)d_in[23];
  float* dout = (float*)d_out;

  char* ws = (char*)d_ws;
  size_t off = 0;
  auto alloc = [&](size_t bytes)->void*{ void* p = ws + off; off += (bytes + 255) & ~(size_t)255; return p; };
  float*  xm      = (float*) alloc(4096ULL*1024*4);
  ushort* xmb     = (ushort*)alloc(4096ULL*1024*2);
  ushort* wihb    = (ushort*)alloc(3072ULL*1024*2);
  float*  gx      = (float*) alloc(4096ULL*3072*4);
  float*  hb      = (float*) alloc(513ULL*8192*4);
  float*  ttpol   = (float*) alloc(4096ULL*8*4);
  ushort* tf      = (ushort*)alloc(4096ULL*KP_*2);
  ushort* w1b     = (ushort*)alloc(8ULL*1024*KP_*2);
  ushort* w2b     = (ushort*)alloc(8ULL*1024*1024*2);
  ushort* h1g     = (ushort*)alloc(4096ULL*1024*2);
  float*  outbuf  = (float*) alloc(4096ULL*1024*4);
  float*  pooled  = (float*) alloc(8192*4);
  float*  csum    = (float*) alloc(64*4);
  float*  pgh     = (float*) alloc(5ULL*8192*4);
  float*  plog    = (float*) alloc(256*4);
  float*  wv      = (float*) alloc(64*4);
  float*  obias   = (float*) alloc(8192*4);
  float*  pooled2 = (float*) alloc(16384*4);
  int*    bar     = (int*)   alloc(256);

  // prep + weight conversions
  k_prep<<<4096, 256, 0, stream>>>(x, amask, xm, xmb);
  k_cvt<<<3072, 256, 0, stream>>>(eWih, wihb, 3072*1024/4);
  k_cvt_w1<<<8192, 256, 0, stream>>>(opW1, w1b);
  k_cvt<<<8192, 256, 0, stream>>>(opW2, w2b, 8*1024*1024/4);

  // gx = x_m @ W_ih^T + b_ih
  { EpiArgs e{}; e.outf = gx; e.bias = ebih; e.ldc = TDK;
    k_gemm<0,false><<<dim3(32,24), 256, 0, stream>>>(xmb, wihb, 1024, 1024, 1024, e); }

  // GRU recurrence (persistent, 64 WGs, 137472B dynamic LDS)
  hipMemsetAsync(bar, 0, 16, stream);
  hipFuncSetAttribute((const void*)k_gru, hipFuncAttributeMaxDynamicSharedMemorySize, 137472);
  k_gru<<<64, 256, 137472, stream>>>(eWhh, ebhh, gx, hb, bar);

  // token feats + concept heads + reductions
  k_tokfeat<<<4096, 256, 0, stream>>>(hb, xm, ttW, ttb, polW, polb, tf, ttpol);
  k_pooled<<<64, 128, 0, stream>>>(hb, xm, pooled);
  k_csum<<<1, 64, 0, stream>>>(ttpol, csum);

  // program generator
  k_ctx<<<32, 256, 0, stream>>>(pooled, csum, c2hW, c2hb, pgh);
  for (int t = 0; t < 4; ++t)
    k_pg<<<128, 256, 0, stream>>>(pgWhh, pgbih, pgbhh, pgh + (size_t)t*8192, pgh + (size_t)(t+1)*8192);
  k_wlogits<<<1, 256, 0, stream>>>(pgh, prjW, prjb, plog, wv);
  k_obias<<<32, 256, 0, stream>>>(wv, opb2, obias);

  // op library: per v, h1 = gelu(tf@W1^T+b1)*w[b,v] ; out += h1@W2^T (+ sum_v w*b2 at init)
  for (int v = 0; v < 8; ++v){
    EpiArgs e1{}; e1.outh = h1g; e1.bias = opb1 + v*1024; e1.wvp = wv; e1.v = v; e1.ldc = 1024;
    k_gemm<1,false><<<dim3(32,8), 256, 0, stream>>>(tf, w1b + (size_t)v*1024*KP_, KP_, KP_, KP_, e1);
    EpiArgs e2{}; e2.outf = outbuf; e2.obias = obias; e2.ldc = 1024;
    if (v == 0) k_gemm<2,true ><<<dim3(32,8), 256, 0, stream>>>(h1g, w2b + (size_t)v*1024*1024, 1024, 1024, 1024, e2);
    else        k_gemm<2,false><<<dim3(32,8), 256, 0, stream>>>(h1g, w2b + (size_t)v*1024*1024, 1024, 1024, 1024, e2);
  }

  // pooling + z + losses
  k_pool2<<<64, 128, 0, stream>>>(outbuf, pooled2);
  k_z<<<1024, 256, 0, stream>>>(pooled2, outW, outB, dout);
  k_losses<<<1, 64, 0, stream>>>(pooled2, plog, dout);
}

// Round 2
// 2751.696 us; speedup vs baseline: 2.5640x; 2.5640x over previous
//
#include <hip/hip_runtime.h>
#include <stdint.h>

// Model dims
#define D_   1024
#define T_   512
#define B_   8
#define V_   8
#define I_   1032
#define KP_  1088   // padded K for token_feats GEMM (17*64)
#define TDK  3072

typedef __attribute__((ext_vector_type(8))) short bf16x8;
typedef __attribute__((ext_vector_type(4))) float f32x4;

__device__ __forceinline__ ushort f2bf(float f){
  union{ unsigned u; float f; } c; c.f = f;
  unsigned u = c.u;
  return (ushort)((u + 0x7FFFu + ((u>>16)&1u)) >> 16);   // RNE
}
__device__ __forceinline__ float bf2f(ushort h){
  union{ unsigned u; float f; } c; c.u = ((unsigned)h) << 16; return c.f;
}
__device__ __forceinline__ float sigmoidf_(float x){ return 1.f/(1.f+__expf(-x)); }

#define WAITV(N) do{ asm volatile("s_waitcnt vmcnt(" #N ")" ::: "memory"); __builtin_amdgcn_sched_barrier(0); }while(0)

// ---------------- prep: x*mask -> f32 + bf16 ----------------
__global__ __launch_bounds__(256) void k_prep(const float* __restrict__ x, const float* __restrict__ mask,
                                              float* __restrict__ xm, ushort* __restrict__ xmb){
  int i = blockIdx.x*256 + threadIdx.x;          // float4 index, total 1048576
  float4 v = ((const float4*)x)[i];
  float mk = mask[i >> 8];                        // token = i*4/1024
  v.x*=mk; v.y*=mk; v.z*=mk; v.w*=mk;
  ((float4*)xm)[i] = v;
  ushort4 h; h.x=f2bf(v.x); h.y=f2bf(v.y); h.z=f2bf(v.z); h.w=f2bf(v.w);
  ((ushort4*)xmb)[i] = h;
}

// ---------------- generic f32 -> bf16 convert ----------------
__global__ __launch_bounds__(256) void k_cvt(const float* __restrict__ in, ushort* __restrict__ out, int n4){
  int i = blockIdx.x*256 + threadIdx.x;
  if (i < n4){
    float4 v = ((const float4*)in)[i];
    ushort4 h; h.x=f2bf(v.x); h.y=f2bf(v.y); h.z=f2bf(v.z); h.w=f2bf(v.w);
    ((ushort4*)out)[i] = h;
  }
}

// op_W1 (8,1024,1032) f32 -> (8,1024,1088) bf16 zero-padded
__global__ __launch_bounds__(256) void k_cvt_w1(const float* __restrict__ w1, ushort* __restrict__ w1b){
  int row = blockIdx.x;                           // 8192 rows
  const float* src = w1 + (size_t)row*I_;
  ushort* dst = w1b + (size_t)row*KP_;
  for (int c = threadIdx.x; c < KP_; c += 256){
    float v = (c < I_) ? src[c] : 0.f;
    dst[c] = f2bf(v);
  }
}

// ---------------- bf16 MFMA GEMM: C(M,N) = A(M,K) @ B(N,K)^T, 128x128 tile ----------------
struct EpiArgs {
  float* outf; ushort* outh;
  const float* bias; const float* wvp; const float* obias;
  int v; int ldc;
};

template<int EPI, bool INIT>
__global__ __launch_bounds__(256) void k_gemm(const ushort* __restrict__ A, const ushort* __restrict__ Bm,
                                              int lda, int ldb, int K, EpiArgs e)
{
  __shared__ ushort As[128][72];   // +8 pad: 2-way-max bank aliasing on b128 reads
  __shared__ ushort Bs[128][72];
  const int tid = threadIdx.x;
  const int w = tid >> 6, l = tid & 63;
  const int wr = w >> 1, wc = w & 1;
  f32x4 acc[4][4] = {};
  const int srow = tid >> 1, shalf = tid & 1;
  const ushort* Ag = A  + (size_t)(blockIdx.x*128 + srow)*lda + shalf*32;
  const ushort* Bg = Bm + (size_t)(blockIdx.y*128 + srow)*ldb + shalf*32;
  ushort* Aw = &As[srow][shalf*32];
  ushort* Bw = &Bs[srow][shalf*32];
  for (int k0 = 0; k0 < K; k0 += 64){
    uint4 a0 = *(const uint4*)(Ag + k0);
    uint4 a1 = *(const uint4*)(Ag + k0 + 8);
    uint4 a2 = *(const uint4*)(Ag + k0 + 16);
    uint4 a3 = *(const uint4*)(Ag + k0 + 24);
    uint4 b0 = *(const uint4*)(Bg + k0);
    uint4 b1 = *(const uint4*)(Bg + k0 + 8);
    uint4 b2 = *(const uint4*)(Bg + k0 + 16);
    uint4 b3 = *(const uint4*)(Bg + k0 + 24);
    __syncthreads();
    *(uint4*)(Aw) = a0; *(uint4*)(Aw+8) = a1; *(uint4*)(Aw+16) = a2; *(uint4*)(Aw+24) = a3;
    *(uint4*)(Bw) = b0; *(uint4*)(Bw+8) = b1; *(uint4*)(Bw+16) = b2; *(uint4*)(Bw+24) = b3;
    __syncthreads();
    #pragma unroll
    for (int kk = 0; kk < 2; ++kk){
      bf16x8 af[4], bfr[4];
      #pragma unroll
      for (int m=0;m<4;++m) af[m]  = *(const bf16x8*)&As[wr*64 + m*16 + (l&15)][kk*32 + ((l>>4)<<3)];
      #pragma unroll
      for (int n=0;n<4;++n) bfr[n] = *(const bf16x8*)&Bs[wc*64 + n*16 + (l&15)][kk*32 + ((l>>4)<<3)];
      #pragma unroll
      for (int m=0;m<4;++m)
        #pragma unroll
        for (int n=0;n<4;++n)
          acc[m][n] = __builtin_amdgcn_mfma_f32_16x16x32_bf16(af[m], bfr[n], acc[m][n], 0, 0, 0);
    }
  }
  // C/D layout (m89): col = lane&15, row = (lane>>4)*4 + reg
  const int row0 = blockIdx.x*128 + wr*64 + ((l>>4)<<2);
  const int col0 = blockIdx.y*128 + wc*64 + (l&15);
  #pragma unroll
  for (int m=0;m<4;++m){
    #pragma unroll
    for (int n=0;n<4;++n){
      f32x4 a = acc[m][n];
      int col = col0 + n*16;
      #pragma unroll
      for (int q=0;q<4;++q){
        int row = row0 + m*16 + q;
        float val = a[q];
        if constexpr (EPI==0){                 // gx: + per-col bias (enc_bih), f32 out
          e.outf[(size_t)row*e.ldc + col] = val + e.bias[col];
        } else if constexpr (EPI==1){          // h1: gelu(acc+b1)*w[b,v] -> bf16
          float xg = val + e.bias[col];
          float g = 0.5f*xg*(1.0f + erff(xg*0.70710678118f));
          e.outh[(size_t)row*e.ldc + col] = f2bf(g * e.wvp[(row>>9)*V_ + e.v]);
        } else {                               // out accumulate across v
          size_t idx = (size_t)row*e.ldc + col;
          float prev = INIT ? e.obias[((row>>9)<<10) + col] : e.outf[idx];
          e.outf[idx] = prev + val;
        }
      }
    }
  }
}

// ---------------- persistent GRU recurrence v2: write-through h exchange, no fences ----------------
// 64 WGs; WG c owns dims [16c,16c+16). W_hh fragments live in 96 VGPRs/thread.
// h stored bf16 (carry stays f32 in regs). Communication: sc0sc1 write-through stores,
// per-WG flag array, sc0sc1 bypass poll + fragment loads. All loop VMEM is inline asm
// with counted vmcnt (compiler emits no VMEM inside the loop).
__global__ __launch_bounds__(256, 1) void k_gru2(const float* __restrict__ whh, const float* __restrict__ bhh,
                                                 const float* __restrict__ gx, ushort* __restrict__ hbf,
                                                 int* __restrict__ flags, const ushort* __restrict__ zbuf)
{
  __shared__ float Red[1536];                     // [4 waves][3 gates][128]
  const int tid = threadIdx.x, c = blockIdx.x;
  const int w = tid >> 6, l = tid & 63;
  const int ar = l & 15, kg = (l >> 4) << 3;

  // hoist W_hh fragments: Bf[g][s] = bf16(whh[g*1024 + c*16 + ar][w*256 + s*32 + kg .. +7])
  bf16x8 Bf[3][8];
  #pragma unroll
  for (int g = 0; g < 3; ++g){
    #pragma unroll
    for (int s = 0; s < 8; ++s){
      const float* src = whh + ((size_t)((g<<10) + (c<<4) + ar))*1024 + (w<<8) + (s<<5) + kg;
      float4 u0 = *(const float4*)src;
      float4 u1 = *(const float4*)(src + 4);
      bf16x8 f;
      f[0]=(short)f2bf(u0.x); f[1]=(short)f2bf(u0.y); f[2]=(short)f2bf(u0.z); f[3]=(short)f2bf(u0.w);
      f[4]=(short)f2bf(u1.x); f[5]=(short)f2bf(u1.y); f[6]=(short)f2bf(u1.z); f[7]=(short)f2bf(u1.w);
      Bf[g][s] = f;
    }
  }
  const int gb_ = (tid >> 4) & 7;                 // batch (waves 2,3: clamped duplicate)
  const int gi_ = tid & 15;
  const int dg  = (c << 4) + gi_;
  const float bhr = bhh[dg], bhz = bhh[1024 + dg], bhn = bhh[2048 + dg];
  float hp = 0.f;
  __syncthreads();                                // drain all pre-loop VMEM (compiler waitcnt before barrier)

  for (int t = 0; t < 512; ++t){
    if (t > 0){
      if (w == 0){                                // wave 0: lane l watches flags[l]
        int fv;
        const int* fp = flags + l;
        do {
          asm volatile("global_load_dword %0, %1, off sc0 sc1" : "=v"(fv) : "v"(fp) : "memory");
          asm volatile("s_waitcnt vmcnt(0)" ::: "memory");
        } while (__any(fv < t));
      }
      __syncthreads();
    }
    // A-fragment coherent loads directly from hbf[t] (bf16, exact MFMA layout)
    bf16x8 af[8];
    const ushort* ab = hbf + ((size_t)t << 13) + (ar << 10) + (w << 8) + kg;
    #pragma unroll
    for (int s = 0; s < 8; ++s){
      const ushort* ap = (ar < 8) ? (ab + (s << 5)) : zbuf;   // pad rows read 16B of zeros
      asm volatile("global_load_dwordx4 %0, %1, off sc0 sc1" : "=v"(af[s]) : "v"(ap) : "memory");
    }
    // gx loads for this step (issued after frags; stay in flight during MFMA)
    float xr, xz, xn;
    {
      const float* g0 = gx + ((size_t)(gb_*512 + t))*TDK + dg;
      asm volatile("global_load_dword %0, %1, off" : "=v"(xr) : "v"(g0)        : "memory");
      asm volatile("global_load_dword %0, %1, off" : "=v"(xz) : "v"(g0 + 1024) : "memory");
      asm volatile("global_load_dword %0, %1, off" : "=v"(xn) : "v"(g0 + 2048) : "memory");
    }
    WAITV(3);                                     // frags retired (in-order), gx outstanding
    f32x4 ac0 = {0.f,0.f,0.f,0.f}, ac1 = {0.f,0.f,0.f,0.f}, ac2 = {0.f,0.f,0.f,0.f};
    #pragma unroll
    for (int s = 0; s < 8; ++s){
      ac0 = __builtin_amdgcn_mfma_f32_16x16x32_bf16(af[s], Bf[0][s], ac0, 0, 0, 0);
      ac1 = __builtin_amdgcn_mfma_f32_16x16x32_bf16(af[s], Bf[1][s], ac1, 0, 0, 0);
      ac2 = __builtin_amdgcn_mfma_f32_16x16x32_bf16(af[s], Bf[2][s], ac2, 0, 0, 0);
    }
    if (l < 32){                                  // rows 0..7 are real batch
      *(f32x4*)(Red + (w*3+0)*128 + l*4) = ac0;
      *(f32x4*)(Red + (w*3+1)*128 + l*4) = ac1;
      *(f32x4*)(Red + (w*3+2)*128 + l*4) = ac2;
    }
    __syncthreads();
    WAITV(0);                                     // gx retired (all waves drain everything)
    if (tid < 128){
      const int idx = (((gb_>>2)<<4) | gi_)*4 + (gb_ & 3);
      float ghr = Red[idx]       + Red[384 + idx]  + Red[768 + idx]  + Red[1152 + idx];
      float ghz = Red[128 + idx] + Red[512 + idx]  + Red[896 + idx]  + Red[1280 + idx];
      float ghn = Red[256 + idx] + Red[640 + idx]  + Red[1024 + idx] + Red[1408 + idx];
      float r  = sigmoidf_(xr + ghr + bhr);
      float z  = sigmoidf_(xz + ghz + bhz);
      float nn = tanhf(xn + r*(ghn + bhn));
      hp = (1.f - z)*nn + z*hp;                   // f32 carry in register
      ushort hv = f2bf(hp);
      ushort* hdst = hbf + ((size_t)(t+1) << 13) + (gb_ << 10) + dg;
      asm volatile("global_store_short %0, %1, off sc0 sc1" :: "v"(hdst), "v"((unsigned)hv) : "memory");
    }
    WAITV(0);                                     // h stores at coherence point (per wave)
    __syncthreads();                              // all waves' stores drained before flag
    if (tid == 0){
      int fv = t + 1;
      const int* fp = flags + c;
      asm volatile("global_store_dword %0, %1, off sc0 sc1" :: "v"(fp), "v"(fv) : "memory");
    }
  }
}

// ---------------- token feats: xe = gru+xm ; tt/pol heads ; build padded bf16 token_feats ----------------
__global__ __launch_bounds__(256) void k_tokfeat(const ushort* __restrict__ hbf, const float* __restrict__ xm,
                                                 const float* __restrict__ ttW, const float* __restrict__ ttb,
                                                 const float* __restrict__ polW, const float* __restrict__ polb,
                                                 ushort* __restrict__ tf, float* __restrict__ ttpol){
  __shared__ float xe[1024];
  const int tok = blockIdx.x;              // b*512 + t
  const int b = tok >> 9, t = tok & 511;
  const int tid = threadIdx.x;
  ushort4 hv4 = *((const ushort4*)(hbf + ((size_t)(t+1) << 13) + ((size_t)b << 10)) + tid);
  float4 xv = ((const float4*)(xm + (size_t)tok*1024))[tid];
  float4 ev; ev.x=bf2f(hv4.x)+xv.x; ev.y=bf2f(hv4.y)+xv.y; ev.z=bf2f(hv4.z)+xv.z; ev.w=bf2f(hv4.w)+xv.w;
  *(float4*)&xe[tid*4] = ev;
  ushort4 eb; eb.x=f2bf(ev.x); eb.y=f2bf(ev.y); eb.z=f2bf(ev.z); eb.w=f2bf(ev.w);
  *(ushort4*)&tf[(size_t)tok*KP_ + tid*4] = eb;
  __syncthreads();
  const int j = tid >> 5, ln = tid & 31;
  const float* Wr = (j < 6) ? (ttW + j*1024) : (polW + (j-6)*1024);
  float acc = 0.f;
  for (int k = ln; k < 1024; k += 32) acc += xe[k]*Wr[k];
  #pragma unroll
  for (int m=16; m>=1; m>>=1) acc += __shfl_xor(acc, m, 32);
  if (ln == 0){
    float val = acc + ((j<6)? ttb[j] : polb[j-6]);
    ttpol[(size_t)tok*8 + j] = val;
    tf[(size_t)tok*KP_ + 1024 + j] = f2bf(val);
  }
  if (tid < 56) tf[(size_t)tok*KP_ + 1032 + tid] = 0;   // K padding
}

// pooled[b][d] = mean_t xe
__global__ __launch_bounds__(128) void k_pooled(const ushort* __restrict__ hbf, const float* __restrict__ xm,
                                                float* __restrict__ pooled){
  const int b = blockIdx.x >> 3;
  const int d = ((blockIdx.x & 7) << 7) + threadIdx.x;
  float s = 0.f;
  for (int t=0; t<512; ++t)
    s += bf2f(hbf[((size_t)(t+1) << 13) + (b << 10) + d]) + xm[((size_t)(b*512+t)<<10) + d];
  pooled[(b<<10)+d] = s * (1.f/512.f);
}

__global__ __launch_bounds__(64) void k_csum(const float* __restrict__ ttpol, float* __restrict__ csum){
  const int b = threadIdx.x >> 3, j = threadIdx.x & 7;
  float s = 0.f;
  for (int t=0; t<512; ++t) s += ttpol[((size_t)(b*512+t)<<3) + j];
  csum[threadIdx.x] = s * (1.f/512.f);
}

// pg_h0 = context @ c2h_W^T + c2h_b
__global__ __launch_bounds__(256) void k_ctx(const float* __restrict__ pooled, const float* __restrict__ csum,
                                             const float* __restrict__ c2hW, const float* __restrict__ c2hb,
                                             float* __restrict__ pgh0){
  const int i = blockIdx.x*256 + threadIdx.x;   // 8192
  const int b = i >> 10, d = i & 1023;
  const float* wr = c2hW + (size_t)d*I_;
  const float* pb = pooled + (b<<10);
  float acc = c2hb[d];
  for (int k=0; k<1024; ++k) acc += pb[k]*wr[k];
  #pragma unroll
  for (int k=0; k<8; ++k) acc += csum[b*8+k]*wr[1024+k];
  pgh0[i] = acc;
}

// one PG GRU step (rnn_in = 0 so gx = pg_bih)
__global__ __launch_bounds__(256) void k_pg(const float* __restrict__ whh, const float* __restrict__ bih,
                                            const float* __restrict__ bhh, const float* __restrict__ hin,
                                            float* __restrict__ hout){
  __shared__ float sh[8][1024];
  const int tid = threadIdx.x;
  for (int f = tid; f < 2048; f += 256) ((float4*)&sh[0][0])[f] = ((const float4*)hin)[f];
  __syncthreads();
  const int d = blockIdx.x*8 + (tid>>5), ln = tid & 31;
  const float* wr = whh + (size_t)d*1024;
  const float* wz = whh + (size_t)(1024+d)*1024;
  const float* wn = whh + (size_t)(2048+d)*1024;
  float ar[8]={0,0,0,0,0,0,0,0}, az[8]={0,0,0,0,0,0,0,0}, an[8]={0,0,0,0,0,0,0,0};
  for (int k = ln; k < 1024; k += 32){
    float r_=wr[k], z_=wz[k], n_=wn[k];
    #pragma unroll
    for (int b=0;b<8;++b){ float h = sh[b][k]; ar[b]+=h*r_; az[b]+=h*z_; an[b]+=h*n_; }
  }
  #pragma unroll
  for (int m=16; m>=1; m>>=1){
    #pragma unroll
    for (int b=0;b<8;++b){ ar[b]+=__shfl_xor(ar[b],m,32); az[b]+=__shfl_xor(az[b],m,32); an[b]+=__shfl_xor(an[b],m,32); }
  }
  if (ln == 0){
    float xr=bih[d], xz=bih[1024+d], xn=bih[2048+d];
    float br=bhh[d], bz=bhh[1024+d], bn=bhh[2048+d];
    #pragma unroll
    for (int b=0;b<8;++b){
      float r = sigmoidf_(xr + ar[b] + br);
      float z = sigmoidf_(xz + az[b] + bz);
      float nn = tanhf(xn + r*(an[b] + bn));
      hout[(b<<10)+d] = (1.f - z)*nn + z*sh[b][d];
    }
  }
}

// program logits + softmax + mean over L -> w[b][v]
__global__ __launch_bounds__(256) void k_wlogits(const float* __restrict__ pgh, const float* __restrict__ prjW,
                                                 const float* __restrict__ prjb, float* __restrict__ plog,
                                                 float* __restrict__ wv){
  __shared__ float lg[256];
  __shared__ float sm[256];
  const int tid = threadIdx.x;
  const int b = tid>>5, li = (tid>>3)&3, v = tid&7;
  const float* h = pgh + (size_t)(li+1)*8192 + (b<<10);
  const float* pw = prjW + (v<<10);
  float acc = prjb[v];
  for (int k=0;k<1024;++k) acc += h[k]*pw[k];
  lg[tid] = acc;         // tid == b*32 + li*8 + v
  plog[tid] = acc;
  __syncthreads();
  if (tid < 32){
    const int bb = tid>>2, ll = tid&3;
    const float* row = &lg[bb*32 + ll*8];
    float mx = row[0];
    #pragma unroll
    for (int u=1;u<8;++u) mx = fmaxf(mx, row[u]);
    float e[8], s=0.f;
    #pragma unroll
    for (int u=0;u<8;++u){ e[u]=__expf(row[u]-mx); s+=e[u]; }
    #pragma unroll
    for (int u=0;u<8;++u) sm[(bb*4+ll)*8+u] = e[u]/s;
  }
  __syncthreads();
  if (tid < 64){
    const int bb = tid>>3, u = tid&7;
    float s = sm[(bb*4+0)*8+u] + sm[(bb*4+1)*8+u] + sm[(bb*4+2)*8+u] + sm[(bb*4+3)*8+u];
    wv[bb*8+u] = 0.25f*s;
  }
}

__global__ __launch_bounds__(256) void k_obias(const float* __restrict__ wv, const float* __restrict__ opb2,
                                               float* __restrict__ obias){
  const int i = blockIdx.x*256 + threadIdx.x;   // 8192
  const int b = i>>10, d = i&1023;
  float s = 0.f;
  #pragma unroll
  for (int v=0; v<8; ++v) s += wv[b*8+v]*opb2[(v<<10)+d];
  obias[i] = s;
}

// pooled2 = [max_t out | mean_t out]
__global__ __launch_bounds__(128) void k_pool2(const float* __restrict__ outb, float* __restrict__ pooled2){
  const int b = blockIdx.x >> 3;
  const int col = ((blockIdx.x & 7) << 7) + threadIdx.x;
  float mx = -3.4e38f, sm = 0.f;
  for (int t=0; t<512; ++t){
    float v = outb[((size_t)(b*512+t)<<10) + col];
    mx = fmaxf(mx, v); sm += v;
  }
  pooled2[((size_t)b<<11) + col] = mx;
  pooled2[((size_t)b<<11) + 1024 + col] = sm*(1.f/512.f);
}

// z = pooled2 @ out_W^T + out_b  -> d_out[0..8191]
__global__ __launch_bounds__(256) void k_z(const float* __restrict__ pooled2, const float* __restrict__ outW,
                                           const float* __restrict__ outBias, float* __restrict__ dout){
  __shared__ float p2[2048];
  const int o = blockIdx.x << 3;
  const int b = o >> 10, dbase = o & 1023;
  for (int f = threadIdx.x; f < 512; f += 256)
    ((float4*)p2)[f] = ((const float4*)(pooled2 + ((size_t)b<<11)))[f];
  __syncthreads();
  const int g = threadIdx.x >> 5, ln = threadIdx.x & 31;
  const int d = dbase + g;
  const float* wr = outW + ((size_t)d << 11);
  float acc = 0.f;
  for (int k = ln; k < 2048; k += 32) acc += p2[k]*wr[k];
  #pragma unroll
  for (int m=16; m>=1; m>>=1) acc += __shfl_xor(acc, m, 32);
  if (ln == 0) dout[(b<<10) + d] = acc + outBias[d];
}

// reuse + contrastive losses (exact f32)
__global__ __launch_bounds__(64) void k_losses(const float* __restrict__ p2g, const float* __restrict__ plog,
                                               float* __restrict__ dout){
  __shared__ float p2n[8], sq[8], pn[8];
  const int l = threadIdx.x;
  { const int b=l>>3, p=l&7; float s=0.f;
    const float* row = p2g + ((size_t)b<<11) + (p<<8);
    for (int k=0;k<256;++k){ float v=row[k]; s += v*v; }
    s += __shfl_xor(s,4,8); s += __shfl_xor(s,2,8); s += __shfl_xor(s,1,8);
    if (p==0) p2n[b] = fmaxf(sqrtf(s), 1e-12f);
  }
  if (l < 8){
    float s=0.f;
    #pragma unroll
    for (int k=0;k<32;++k){ float v=plog[l*32+k]; s+=v*v; }
    sq[l]=s; pn[l]=fmaxf(sqrtf(s),1e-12f);
  }
  __syncthreads();
  const int i=l>>3, j=l&7;
  const float* ri = p2g + ((size_t)i<<11);
  const float* rj = p2g + ((size_t)j<<11);
  float dot=0.f; for (int k=0;k<2048;++k) dot += ri[k]*rj[k];
  float sim = dot/(p2n[i]*p2n[j]);
  float pd=0.f;
  #pragma unroll
  for (int k=0;k<32;++k) pd += plog[i*32+k]*plog[j*32+k];
  float d2 = fmaxf(sq[i]+sq[j]-2.f*pd, 0.f);
  float dist = (d2>0.f)? sqrtf(d2) : 0.f;
  float psim = pd/(pn[i]*pn[j]);
  float pos = (sim>0.7f)?1.f:0.f, neg = (sim<0.7f)?1.f:0.f;
  float rs = sim*dist, ps=(1.f-psim)*pos, ns=fmaxf(psim-0.5f,0.f)*neg, pc=pos, nc=neg;
  #pragma unroll
  for (int m=32; m>=1; m>>=1){
    rs+=__shfl_xor(rs,m); ps+=__shfl_xor(ps,m); ns+=__shfl_xor(ns,m);
    pc+=__shfl_xor(pc,m); nc+=__shfl_xor(nc,m);
  }
  if (l==0){ dout[8192]=rs*(1.f/64.f); dout[8193]=(ps+ns)/(pc+nc+1e-6f); }
}

// ============================ host ============================
extern "C" void kernel_launch(void* const* d_in, const int* in_sizes, int n_in,
                              void* d_out, int out_size, void* d_ws, size_t ws_size,
                              hipStream_t stream) {
  (void)in_sizes; (void)n_in; (void)out_size; (void)ws_size;
  const float* x     = (const float*)d_in[0];
  const float* amask = (const float*)d_in[1];
  const float* eWih  = (const float*)d_in[2];
  const float* eWhh  = (const float*)d_in[3];
  const float* ebih  = (const float*)d_in[4];
  const float* ebhh  = (const float*)d_in[5];
  const float* ttW   = (const float*)d_in[6];
  const float* ttb   = (const float*)d_in[7];
  const float* polW  = (const float*)d_in[8];
  const float* polb  = (const float*)d_in[9];
  const float* c2hW  = (const float*)d_in[10];
  const float* c2hb  = (const float*)d_in[11];
  const float* pgWhh = (const float*)d_in[13];
  const float* pgbih = (const float*)d_in[14];
  const float* pgbhh = (const float*)d_in[15];
  const float* prjW  = (const float*)d_in[16];
  const float* prjb  = (const float*)d_in[17];
  const float* opW1  = (const float*)d_in[18];
  const float* opb1  = (const float*)d_in[19];
  const float* opW2  = (const float*)d_in[20];
  const float* opb2  = (const float*)d_in[21];
  const float* outW  = (const float*)d_in[22];
  const float* outB  = (const float*)d_in[23];
  float* dout = (float*)d_out;

  char* ws = (char*)d_ws;
  size_t off = 0;
  auto alloc = [&](size_t bytes)->void*{ void* p = ws + off; off += (bytes + 255) & ~(size_t)255; return p; };
  float*  xm      = (float*) alloc(4096ULL*1024*4);
  ushort* xmb     = (ushort*)alloc(4096ULL*1024*2);
  ushort* wihb    = (ushort*)alloc(3072ULL*1024*2);
  float*  gx      = (float*) alloc(4096ULL*3072*4);
  ushort* hbf     = (ushort*)alloc(513ULL*8192*2);
  float*  ttpol   = (float*) alloc(4096ULL*8*4);
  ushort* tf      = (ushort*)alloc(4096ULL*KP_*2);
  ushort* w1b     = (ushort*)alloc(8ULL*1024*KP_*2);
  ushort* w2b     = (ushort*)alloc(8ULL*1024*1024*2);
  ushort* h1g     = (ushort*)alloc(4096ULL*1024*2);
  float*  outbuf  = (float*) alloc(4096ULL*1024*4);
  float*  pooled  = (float*) alloc(8192*4);
  float*  csum    = (float*) alloc(64*4);
  float*  pgh     = (float*) alloc(5ULL*8192*4);
  float*  plog    = (float*) alloc(256*4);
  float*  wv      = (float*) alloc(64*4);
  float*  obias   = (float*) alloc(8192*4);
  float*  pooled2 = (float*) alloc(16384*4);
  int*    flags   = (int*)   alloc(256);
  ushort* zbuf    = (ushort*)alloc(256);

  // prep + weight conversions + exchange-buffer init
  hipMemsetAsync(flags, 0, 64*4, stream);
  hipMemsetAsync(hbf, 0, 8192*2, stream);        // h at t=0 is zero
  hipMemsetAsync(zbuf, 0, 256, stream);
  k_prep<<<4096, 256, 0, stream>>>(x, amask, xm, xmb);
  k_cvt<<<3072, 256, 0, stream>>>(eWih, wihb, 3072*1024/4);
  k_cvt_w1<<<8192, 256, 0, stream>>>(opW1, w1b);
  k_cvt<<<8192, 256, 0, stream>>>(opW2, w2b, 8*1024*1024/4);

  // gx = x_m @ W_ih^T + b_ih
  { EpiArgs e{}; e.outf = gx; e.bias = ebih; e.ldc = TDK;
    k_gemm<0,false><<<dim3(32,24), 256, 0, stream>>>(xmb, wihb, 1024, 1024, 1024, e); }

  // GRU recurrence (persistent, 64 WGs, fence-free exchange)
  k_gru2<<<64, 256, 0, stream>>>(eWhh, ebhh, gx, hbf, flags, zbuf);

  // token feats + concept heads + reductions
  k_tokfeat<<<4096, 256, 0, stream>>>(hbf, xm, ttW, ttb, polW, polb, tf, ttpol);
  k_pooled<<<64, 128, 0, stream>>>(hbf, xm, pooled);
  k_csum<<<1, 64, 0, stream>>>(ttpol, csum);

  // program generator
  k_ctx<<<32, 256, 0, stream>>>(pooled, csum, c2hW, c2hb, pgh);
  for (int t = 0; t < 4; ++t)
    k_pg<<<128, 256, 0, stream>>>(pgWhh, pgbih, pgbhh, pgh + (size_t)t*8192, pgh + (size_t)(t+1)*8192);
  k_wlogits<<<1, 256, 0, stream>>>(pgh, prjW, prjb, plog, wv);
  k_obias<<<32, 256, 0, stream>>>(wv, opb2, obias);

  // op library: per v, h1 = gelu(tf@W1^T+b1)*w[b,v] ; out += h1@W2^T (+ sum_v w*b2 at init)
  for (int v = 0; v < 8; ++v){
    EpiArgs e1{}; e1.outh = h1g; e1.bias = opb1 + v*1024; e1.wvp = wv; e1.v = v; e1.ldc = 1024;
    k_gemm<1,false><<<dim3(32,8), 256, 0, stream>>>(tf, w1b + (size_t)v*1024*KP_, KP_, KP_, KP_, e1);
    EpiArgs e2{}; e2.outf = outbuf; e2.obias = obias; e2.ldc = 1024;
    if (v == 0) k_gemm<2,true ><<<dim3(32,8), 256, 0, stream>>>(h1g, w2b + (size_t)v*1024*1024, 1024, 1024, 1024, e2);
    else        k_gemm<2,false><<<dim3(32,8), 256, 0, stream>>>(h1g, w2b + (size_t)v*1024*1024, 1024, 1024, 1024, e2);
  }

  // pooling + z + losses
  k_pool2<<<64, 128, 0, stream>>>(outbuf, pooled2);
  k_z<<<1024, 256, 0, stream>>>(pooled2, outW, outB, dout);
  k_losses<<<1, 64, 0, stream>>>(pooled2, plog, dout);
}

// Round 3
// 2184.128 us; speedup vs baseline: 3.2302x; 1.2599x over previous
//
#include <hip/hip_runtime.h>
#include <stdint.h>

// Model dims
#define D_   1024
#define T_   512
#define B_   8
#define V_   8
#define I_   1032
#define KP_  1088   // padded K for token_feats GEMM (17*64)
#define TDK  3072

typedef __attribute__((ext_vector_type(8))) short bf16x8;
typedef __attribute__((ext_vector_type(4))) float f32x4;

__device__ __forceinline__ ushort f2bf(float f){
  union{ unsigned u; float f; } c; c.f = f;
  unsigned u = c.u;
  return (ushort)((u + 0x7FFFu + ((u>>16)&1u)) >> 16);   // RNE
}
__device__ __forceinline__ float bf2f(ushort h){
  union{ unsigned u; float f; } c; c.u = ((unsigned)h) << 16; return c.f;
}
__device__ __forceinline__ float sigmoidf_(float x){ return 1.f/(1.f+__expf(-x)); }

#define WAITV(N) do{ asm volatile("s_waitcnt vmcnt(" #N ")" ::: "memory"); __builtin_amdgcn_sched_barrier(0); }while(0)

// ---------------- prep: x*mask -> f32 + bf16 ----------------
__global__ __launch_bounds__(256) void k_prep(const float* __restrict__ x, const float* __restrict__ mask,
                                              float* __restrict__ xm, ushort* __restrict__ xmb){
  int i = blockIdx.x*256 + threadIdx.x;          // float4 index, total 1048576
  float4 v = ((const float4*)x)[i];
  float mk = mask[i >> 8];                        // token = i*4/1024
  v.x*=mk; v.y*=mk; v.z*=mk; v.w*=mk;
  ((float4*)xm)[i] = v;
  ushort4 h; h.x=f2bf(v.x); h.y=f2bf(v.y); h.z=f2bf(v.z); h.w=f2bf(v.w);
  ((ushort4*)xmb)[i] = h;
}

// init h slot 0: value bf16(0), tag 1
__global__ __launch_bounds__(256) void k_hinit(unsigned* __restrict__ hw){
  hw[blockIdx.x*256 + threadIdx.x] = 1u;
}

// ---------------- generic f32 -> bf16 convert ----------------
__global__ __launch_bounds__(256) void k_cvt(const float* __restrict__ in, ushort* __restrict__ out, int n4){
  int i = blockIdx.x*256 + threadIdx.x;
  if (i < n4){
    float4 v = ((const float4*)in)[i];
    ushort4 h; h.x=f2bf(v.x); h.y=f2bf(v.y); h.z=f2bf(v.z); h.w=f2bf(v.w);
    ((ushort4*)out)[i] = h;
  }
}

// op_W1 (8,1024,1032) f32 -> (8,1024,1088) bf16 zero-padded
__global__ __launch_bounds__(256) void k_cvt_w1(const float* __restrict__ w1, ushort* __restrict__ w1b){
  int row = blockIdx.x;                           // 8192 rows
  const float* src = w1 + (size_t)row*I_;
  ushort* dst = w1b + (size_t)row*KP_;
  for (int c = threadIdx.x; c < KP_; c += 256){
    float v = (c < I_) ? src[c] : 0.f;
    dst[c] = f2bf(v);
  }
}

// ---------------- bf16 MFMA GEMM: C(M,N) = A(M,K) @ B(N,K)^T, 128x128 tile ----------------
struct EpiArgs {
  float* outf; ushort* outh;
  const float* bias; const float* wvp; const float* obias;
  int v; int ldc;
};

template<int EPI, bool INIT>
__global__ __launch_bounds__(256) void k_gemm(const ushort* __restrict__ A, const ushort* __restrict__ Bm,
                                              int lda, int ldb, int K, EpiArgs e)
{
  __shared__ ushort As[128][72];   // +8 pad: 2-way-max bank aliasing on b128 reads
  __shared__ ushort Bs[128][72];
  const int tid = threadIdx.x;
  const int w = tid >> 6, l = tid & 63;
  const int wr = w >> 1, wc = w & 1;
  f32x4 acc[4][4] = {};
  const int srow = tid >> 1, shalf = tid & 1;
  const ushort* Ag = A  + (size_t)(blockIdx.x*128 + srow)*lda + shalf*32;
  const ushort* Bg = Bm + (size_t)(blockIdx.y*128 + srow)*ldb + shalf*32;
  ushort* Aw = &As[srow][shalf*32];
  ushort* Bw = &Bs[srow][shalf*32];
  for (int k0 = 0; k0 < K; k0 += 64){
    uint4 a0 = *(const uint4*)(Ag + k0);
    uint4 a1 = *(const uint4*)(Ag + k0 + 8);
    uint4 a2 = *(const uint4*)(Ag + k0 + 16);
    uint4 a3 = *(const uint4*)(Ag + k0 + 24);
    uint4 b0 = *(const uint4*)(Bg + k0);
    uint4 b1 = *(const uint4*)(Bg + k0 + 8);
    uint4 b2 = *(const uint4*)(Bg + k0 + 16);
    uint4 b3 = *(const uint4*)(Bg + k0 + 24);
    __syncthreads();
    *(uint4*)(Aw) = a0; *(uint4*)(Aw+8) = a1; *(uint4*)(Aw+16) = a2; *(uint4*)(Aw+24) = a3;
    *(uint4*)(Bw) = b0; *(uint4*)(Bw+8) = b1; *(uint4*)(Bw+16) = b2; *(uint4*)(Bw+24) = b3;
    __syncthreads();
    #pragma unroll
    for (int kk = 0; kk < 2; ++kk){
      bf16x8 af[4], bfr[4];
      #pragma unroll
      for (int m=0;m<4;++m) af[m]  = *(const bf16x8*)&As[wr*64 + m*16 + (l&15)][kk*32 + ((l>>4)<<3)];
      #pragma unroll
      for (int n=0;n<4;++n) bfr[n] = *(const bf16x8*)&Bs[wc*64 + n*16 + (l&15)][kk*32 + ((l>>4)<<3)];
      #pragma unroll
      for (int m=0;m<4;++m)
        #pragma unroll
        for (int n=0;n<4;++n)
          acc[m][n] = __builtin_amdgcn_mfma_f32_16x16x32_bf16(af[m], bfr[n], acc[m][n], 0, 0, 0);
    }
  }
  // C/D layout (m89): col = lane&15, row = (lane>>4)*4 + reg
  const int row0 = blockIdx.x*128 + wr*64 + ((l>>4)<<2);
  const int col0 = blockIdx.y*128 + wc*64 + (l&15);
  #pragma unroll
  for (int m=0;m<4;++m){
    #pragma unroll
    for (int n=0;n<4;++n){
      f32x4 a = acc[m][n];
      int col = col0 + n*16;
      #pragma unroll
      for (int q=0;q<4;++q){
        int row = row0 + m*16 + q;
        float val = a[q];
        if constexpr (EPI==0){                 // gx: + per-col bias (enc_bih), f32 out
          e.outf[(size_t)row*e.ldc + col] = val + e.bias[col];
        } else if constexpr (EPI==1){          // h1: gelu(acc+b1)*w[b,v] -> bf16
          float xg = val + e.bias[col];
          float g = 0.5f*xg*(1.0f + erff(xg*0.70710678118f));
          e.outh[(size_t)row*e.ldc + col] = f2bf(g * e.wvp[(row>>9)*V_ + e.v]);
        } else {                               // out accumulate across v
          size_t idx = (size_t)row*e.ldc + col;
          float prev = INIT ? e.obias[((row>>9)<<10) + col] : e.outf[idx];
          e.outf[idx] = prev + val;
        }
      }
    }
  }
}

// ---------------- persistent GRU recurrence v3: tag-in-data exchange, single round trip ----------------
// h word for step slot s: (bf16(h)<<16) | (s+1).  Consumer at step t reads slot t, expects tag t+1.
// No flags, no store-ack wait: readiness == data arrival. Stale replay data is tag- AND value-identical
// (deterministic recurrence), so early reads are benign.
__global__ __launch_bounds__(256, 1) void k_gru3(const float* __restrict__ whh, const float* __restrict__ bhh,
                                                 const float* __restrict__ gx, unsigned* __restrict__ hw)
{
  __shared__ float Red[1536];                     // [4 waves][3 gates][128]
  const int tid = threadIdx.x, c = blockIdx.x;
  const int w = tid >> 6, l = tid & 63;
  const int ar = l & 15, kg = (l >> 4) << 3;

  // hoist W_hh fragments: Bf[g][s] = bf16(whh[g*1024 + c*16 + ar][w*256 + s*32 + kg .. +7])
  bf16x8 Bf[3][8];
  #pragma unroll
  for (int g = 0; g < 3; ++g){
    #pragma unroll
    for (int s = 0; s < 8; ++s){
      const float* src = whh + ((size_t)((g<<10) + (c<<4) + ar))*1024 + (w<<8) + (s<<5) + kg;
      float4 u0 = *(const float4*)src;
      float4 u1 = *(const float4*)(src + 4);
      bf16x8 f;
      f[0]=(short)f2bf(u0.x); f[1]=(short)f2bf(u0.y); f[2]=(short)f2bf(u0.z); f[3]=(short)f2bf(u0.w);
      f[4]=(short)f2bf(u1.x); f[5]=(short)f2bf(u1.y); f[6]=(short)f2bf(u1.z); f[7]=(short)f2bf(u1.w);
      Bf[g][s] = f;
    }
  }
  const int gb_ = (tid >> 4) & 7;                 // batch (waves 2,3: duplicate, unused for gates)
  const int gi_ = tid & 15;
  const int dg  = (c << 4) + gi_;
  const float bhr = bhh[dg], bhz = bhh[1024 + dg], bhn = bhh[2048 + dg];
  float hp = 0.f;
  __syncthreads();

  for (int t = 0; t < 512; ++t){
    // gx loads for this step (issued first; overlap with h poll)
    float xr, xz, xn;
    {
      const float* g0 = gx + ((size_t)(gb_*512 + t))*TDK + dg;
      asm volatile("global_load_dword %0, %1, off" : "=v"(xr) : "v"(g0)        : "memory");
      asm volatile("global_load_dword %0, %1, off" : "=v"(xz) : "v"(g0 + 1024) : "memory");
      asm volatile("global_load_dword %0, %1, off" : "=v"(xn) : "v"(g0 + 2048) : "memory");
    }
    // poll tagged h words for slot t (lanes ar<8 only; rows 8..15 are zero-pad)
    uint4 rw[16];
    const unsigned tagv = (unsigned)(t + 1);
    if (ar < 8){
      const unsigned* hb0 = hw + ((size_t)t << 13) + (ar << 10) + (w << 8) + kg;
      while (true){
        #pragma unroll
        for (int s = 0; s < 8; ++s){
          asm volatile("global_load_dwordx4 %0, %1, off sc0 sc1" : "=v"(rw[2*s])   : "v"(hb0 + (s<<5))     : "memory");
          asm volatile("global_load_dwordx4 %0, %1, off sc0 sc1" : "=v"(rw[2*s+1]) : "v"(hb0 + (s<<5) + 4) : "memory");
        }
        WAITV(0);
        unsigned acc = 0;
        #pragma unroll
        for (int q = 0; q < 16; ++q){
          acc |= (rw[q].x ^ tagv); acc |= (rw[q].y ^ tagv);
          acc |= (rw[q].z ^ tagv); acc |= (rw[q].w ^ tagv);
        }
        if (__all((acc & 0xFFFFu) == 0u)) break;
      }
    }
    WAITV(0);                                     // gx drained (no-op for waves that polled)
    // repack high halves -> bf16x8 fragments
    f32x4 ac0 = {0.f,0.f,0.f,0.f}, ac1 = {0.f,0.f,0.f,0.f}, ac2 = {0.f,0.f,0.f,0.f};
    if (ar < 8){
      #pragma unroll
      for (int s = 0; s < 8; ++s){
        unsigned d0 = __builtin_amdgcn_perm(rw[2*s].y,   rw[2*s].x,   0x07060302u);
        unsigned d1 = __builtin_amdgcn_perm(rw[2*s].w,   rw[2*s].z,   0x07060302u);
        unsigned d2 = __builtin_amdgcn_perm(rw[2*s+1].y, rw[2*s+1].x, 0x07060302u);
        unsigned d3 = __builtin_amdgcn_perm(rw[2*s+1].w, rw[2*s+1].z, 0x07060302u);
        union { unsigned u[4]; bf16x8 v; } cv;
        cv.u[0]=d0; cv.u[1]=d1; cv.u[2]=d2; cv.u[3]=d3;
        bf16x8 af = cv.v;
        ac0 = __builtin_amdgcn_mfma_f32_16x16x32_bf16(af, Bf[0][s], ac0, 0, 0, 0);
        ac1 = __builtin_amdgcn_mfma_f32_16x16x32_bf16(af, Bf[1][s], ac1, 0, 0, 0);
        ac2 = __builtin_amdgcn_mfma_f32_16x16x32_bf16(af, Bf[2][s], ac2, 0, 0, 0);
      }
    }
    if (l < 32){                                  // rows 0..7 are real batch
      *(f32x4*)(Red + (w*3+0)*128 + l*4) = ac0;
      *(f32x4*)(Red + (w*3+1)*128 + l*4) = ac1;
      *(f32x4*)(Red + (w*3+2)*128 + l*4) = ac2;
    }
    __syncthreads();
    if (tid < 128){
      const int idx = (((gb_>>2)<<4) | gi_)*4 + (gb_ & 3);
      float ghr = Red[idx]       + Red[384 + idx]  + Red[768 + idx]  + Red[1152 + idx];
      float ghz = Red[128 + idx] + Red[512 + idx]  + Red[896 + idx]  + Red[1280 + idx];
      float ghn = Red[256 + idx] + Red[640 + idx]  + Red[1024 + idx] + Red[1408 + idx];
      float r  = sigmoidf_(xr + ghr + bhr);
      float z  = sigmoidf_(xz + ghz + bhz);
      float nn = tanhf(xn + r*(ghn + bhn));
      hp = (1.f - z)*nn + z*hp;                   // f32 carry in register
      unsigned word = (((unsigned)f2bf(hp)) << 16) | (unsigned)(t + 2);
      unsigned* hdst = hw + ((size_t)(t+1) << 13) + (gb_ << 10) + dg;
      asm volatile("global_store_dword %0, %1, off sc0 sc1" :: "v"(hdst), "v"(word) : "memory");
    }
    __syncthreads();                              // protect Red (next step's writes) + keep waves loosely synced
  }
}

// ---------------- token feats: xe = gru+xm ; tt/pol heads ; build padded bf16 token_feats ----------------
__global__ __launch_bounds__(256) void k_tokfeat(const unsigned* __restrict__ hw, const float* __restrict__ xm,
                                                 const float* __restrict__ ttW, const float* __restrict__ ttb,
                                                 const float* __restrict__ polW, const float* __restrict__ polb,
                                                 ushort* __restrict__ tf, float* __restrict__ ttpol){
  __shared__ float xe[1024];
  const int tok = blockIdx.x;              // b*512 + t
  const int b = tok >> 9, t = tok & 511;
  const int tid = threadIdx.x;
  uint4 hv4 = *((const uint4*)(hw + ((size_t)(t+1) << 13) + ((size_t)b << 10)) + tid);
  float4 xv = ((const float4*)(xm + (size_t)tok*1024))[tid];
  float4 ev;
  ev.x = bf2f((ushort)(hv4.x >> 16)) + xv.x;
  ev.y = bf2f((ushort)(hv4.y >> 16)) + xv.y;
  ev.z = bf2f((ushort)(hv4.z >> 16)) + xv.z;
  ev.w = bf2f((ushort)(hv4.w >> 16)) + xv.w;
  *(float4*)&xe[tid*4] = ev;
  ushort4 eb; eb.x=f2bf(ev.x); eb.y=f2bf(ev.y); eb.z=f2bf(ev.z); eb.w=f2bf(ev.w);
  *(ushort4*)&tf[(size_t)tok*KP_ + tid*4] = eb;
  __syncthreads();
  const int j = tid >> 5, ln = tid & 31;
  const float* Wr = (j < 6) ? (ttW + j*1024) : (polW + (j-6)*1024);
  float acc = 0.f;
  for (int k = ln; k < 1024; k += 32) acc += xe[k]*Wr[k];
  #pragma unroll
  for (int m=16; m>=1; m>>=1) acc += __shfl_xor(acc, m, 32);
  if (ln == 0){
    float val = acc + ((j<6)? ttb[j] : polb[j-6]);
    ttpol[(size_t)tok*8 + j] = val;
    tf[(size_t)tok*KP_ + 1024 + j] = f2bf(val);
  }
  if (tid < 56) tf[(size_t)tok*KP_ + 1032 + tid] = 0;   // K padding
}

// pooled[b][d] = mean_t xe
__global__ __launch_bounds__(128) void k_pooled(const unsigned* __restrict__ hw, const float* __restrict__ xm,
                                                float* __restrict__ pooled){
  const int b = blockIdx.x >> 3;
  const int d = ((blockIdx.x & 7) << 7) + threadIdx.x;
  float s = 0.f;
  for (int t=0; t<512; ++t)
    s += bf2f((ushort)(hw[((size_t)(t+1) << 13) + (b << 10) + d] >> 16)) + xm[((size_t)(b*512+t)<<10) + d];
  pooled[(b<<10)+d] = s * (1.f/512.f);
}

__global__ __launch_bounds__(64) void k_csum(const float* __restrict__ ttpol, float* __restrict__ csum){
  const int b = threadIdx.x >> 3, j = threadIdx.x & 7;
  float s = 0.f;
  for (int t=0; t<512; ++t) s += ttpol[((size_t)(b*512+t)<<3) + j];
  csum[threadIdx.x] = s * (1.f/512.f);
}

// pg_h0 = context @ c2h_W^T + c2h_b
__global__ __launch_bounds__(256) void k_ctx(const float* __restrict__ pooled, const float* __restrict__ csum,
                                             const float* __restrict__ c2hW, const float* __restrict__ c2hb,
                                             float* __restrict__ pgh0){
  const int i = blockIdx.x*256 + threadIdx.x;   // 8192
  const int b = i >> 10, d = i & 1023;
  const float* wr = c2hW + (size_t)d*I_;
  const float* pb = pooled + (b<<10);
  float acc = c2hb[d];
  for (int k=0; k<1024; ++k) acc += pb[k]*wr[k];
  #pragma unroll
  for (int k=0; k<8; ++k) acc += csum[b*8+k]*wr[1024+k];
  pgh0[i] = acc;
}

// one PG GRU step (rnn_in = 0 so gx = pg_bih)
__global__ __launch_bounds__(256) void k_pg(const float* __restrict__ whh, const float* __restrict__ bih,
                                            const float* __restrict__ bhh, const float* __restrict__ hin,
                                            float* __restrict__ hout){
  __shared__ float sh[8][1024];
  const int tid = threadIdx.x;
  for (int f = tid; f < 2048; f += 256) ((float4*)&sh[0][0])[f] = ((const float4*)hin)[f];
  __syncthreads();
  const int d = blockIdx.x*8 + (tid>>5), ln = tid & 31;
  const float* wr = whh + (size_t)d*1024;
  const float* wz = whh + (size_t)(1024+d)*1024;
  const float* wn = whh + (size_t)(2048+d)*1024;
  float ar[8]={0,0,0,0,0,0,0,0}, az[8]={0,0,0,0,0,0,0,0}, an[8]={0,0,0,0,0,0,0,0};
  for (int k = ln; k < 1024; k += 32){
    float r_=wr[k], z_=wz[k], n_=wn[k];
    #pragma unroll
    for (int b=0;b<8;++b){ float h = sh[b][k]; ar[b]+=h*r_; az[b]+=h*z_; an[b]+=h*n_; }
  }
  #pragma unroll
  for (int m=16; m>=1; m>>=1){
    #pragma unroll
    for (int b=0;b<8;++b){ ar[b]+=__shfl_xor(ar[b],m,32); az[b]+=__shfl_xor(az[b],m,32); an[b]+=__shfl_xor(an[b],m,32); }
  }
  if (ln == 0){
    float xr=bih[d], xz=bih[1024+d], xn=bih[2048+d];
    float br=bhh[d], bz=bhh[1024+d], bn=bhh[2048+d];
    #pragma unroll
    for (int b=0;b<8;++b){
      float r = sigmoidf_(xr + ar[b] + br);
      float z = sigmoidf_(xz + az[b] + bz);
      float nn = tanhf(xn + r*(an[b] + bn));
      hout[(b<<10)+d] = (1.f - z)*nn + z*sh[b][d];
    }
  }
}

// program logits + softmax + mean over L -> w[b][v]
__global__ __launch_bounds__(256) void k_wlogits(const float* __restrict__ pgh, const float* __restrict__ prjW,
                                                 const float* __restrict__ prjb, float* __restrict__ plog,
                                                 float* __restrict__ wv){
  __shared__ float lg[256];
  __shared__ float sm[256];
  const int tid = threadIdx.x;
  const int b = tid>>5, li = (tid>>3)&3, v = tid&7;
  const float* h = pgh + (size_t)(li+1)*8192 + (b<<10);
  const float* pw = prjW + (v<<10);
  float acc = prjb[v];
  for (int k=0;k<1024;++k) acc += h[k]*pw[k];
  lg[tid] = acc;         // tid == b*32 + li*8 + v
  plog[tid] = acc;
  __syncthreads();
  if (tid < 32){
    const int bb = tid>>2, ll = tid&3;
    const float* row = &lg[bb*32 + ll*8];
    float mx = row[0];
    #pragma unroll
    for (int u=1;u<8;++u) mx = fmaxf(mx, row[u]);
    float e[8], s=0.f;
    #pragma unroll
    for (int u=0;u<8;++u){ e[u]=__expf(row[u]-mx); s+=e[u]; }
    #pragma unroll
    for (int u=0;u<8;++u) sm[(bb*4+ll)*8+u] = e[u]/s;
  }
  __syncthreads();
  if (tid < 64){
    const int bb = tid>>3, u = tid&7;
    float s = sm[(bb*4+0)*8+u] + sm[(bb*4+1)*8+u] + sm[(bb*4+2)*8+u] + sm[(bb*4+3)*8+u];
    wv[bb*8+u] = 0.25f*s;
  }
}

__global__ __launch_bounds__(256) void k_obias(const float* __restrict__ wv, const float* __restrict__ opb2,
                                               float* __restrict__ obias){
  const int i = blockIdx.x*256 + threadIdx.x;   // 8192
  const int b = i>>10, d = i&1023;
  float s = 0.f;
  #pragma unroll
  for (int v=0; v<8; ++v) s += wv[b*8+v]*opb2[(v<<10)+d];
  obias[i] = s;
}

// pooled2 = [max_t out | mean_t out]
__global__ __launch_bounds__(128) void k_pool2(const float* __restrict__ outb, float* __restrict__ pooled2){
  const int b = blockIdx.x >> 3;
  const int col = ((blockIdx.x & 7) << 7) + threadIdx.x;
  float mx = -3.4e38f, sm = 0.f;
  for (int t=0; t<512; ++t){
    float v = outb[((size_t)(b*512+t)<<10) + col];
    mx = fmaxf(mx, v); sm += v;
  }
  pooled2[((size_t)b<<11) + col] = mx;
  pooled2[((size_t)b<<11) + 1024 + col] = sm*(1.f/512.f);
}

// z = pooled2 @ out_W^T + out_b  -> d_out[0..8191]
__global__ __launch_bounds__(256) void k_z(const float* __restrict__ pooled2, const float* __restrict__ outW,
                                           const float* __restrict__ outBias, float* __restrict__ dout){
  __shared__ float p2[2048];
  const int o = blockIdx.x << 3;
  const int b = o >> 10, dbase = o & 1023;
  for (int f = threadIdx.x; f < 512; f += 256)
    ((float4*)p2)[f] = ((const float4*)(pooled2 + ((size_t)b<<11)))[f];
  __syncthreads();
  const int g = threadIdx.x >> 5, ln = threadIdx.x & 31;
  const int d = dbase + g;
  const float* wr = outW + ((size_t)d << 11);
  float acc = 0.f;
  for (int k = ln; k < 2048; k += 32) acc += p2[k]*wr[k];
  #pragma unroll
  for (int m=16; m>=1; m>>=1) acc += __shfl_xor(acc, m, 32);
  if (ln == 0) dout[(b<<10) + d] = acc + outBias[d];
}

// reuse + contrastive losses (exact f32)
__global__ __launch_bounds__(64) void k_losses(const float* __restrict__ p2g, const float* __restrict__ plog,
                                               float* __restrict__ dout){
  __shared__ float p2n[8], sq[8], pn[8];
  const int l = threadIdx.x;
  { const int b=l>>3, p=l&7; float s=0.f;
    const float* row = p2g + ((size_t)b<<11) + (p<<8);
    for (int k=0;k<256;++k){ float v=row[k]; s += v*v; }
    s += __shfl_xor(s,4,8); s += __shfl_xor(s,2,8); s += __shfl_xor(s,1,8);
    if (p==0) p2n[b] = fmaxf(sqrtf(s), 1e-12f);
  }
  if (l < 8){
    float s=0.f;
    #pragma unroll
    for (int k=0;k<32;++k){ float v=plog[l*32+k]; s+=v*v; }
    sq[l]=s; pn[l]=fmaxf(sqrtf(s),1e-12f);
  }
  __syncthreads();
  const int i=l>>3, j=l&7;
  const float* ri = p2g + ((size_t)i<<11);
  const float* rj = p2g + ((size_t)j<<11);
  float dot=0.f; for (int k=0;k<2048;++k) dot += ri[k]*rj[k];
  float sim = dot/(p2n[i]*p2n[j]);
  float pd=0.f;
  #pragma unroll
  for (int k=0;k<32;++k) pd += plog[i*32+k]*plog[j*32+k];
  float d2 = fmaxf(sq[i]+sq[j]-2.f*pd, 0.f);
  float dist = (d2>0.f)? sqrtf(d2) : 0.f;
  float psim = pd/(pn[i]*pn[j]);
  float pos = (sim>0.7f)?1.f:0.f, neg = (sim<0.7f)?1.f:0.f;
  float rs = sim*dist, ps=(1.f-psim)*pos, ns=fmaxf(psim-0.5f,0.f)*neg, pc=pos, nc=neg;
  #pragma unroll
  for (int m=32; m>=1; m>>=1){
    rs+=__shfl_xor(rs,m); ps+=__shfl_xor(ps,m); ns+=__shfl_xor(ns,m);
    pc+=__shfl_xor(pc,m); nc+=__shfl_xor(nc,m);
  }
  if (l==0){ dout[8192]=rs*(1.f/64.f); dout[8193]=(ps+ns)/(pc+nc+1e-6f); }
}

// ============================ host ============================
extern "C" void kernel_launch(void* const* d_in, const int* in_sizes, int n_in,
                              void* d_out, int out_size, void* d_ws, size_t ws_size,
                              hipStream_t stream) {
  (void)in_sizes; (void)n_in; (void)out_size; (void)ws_size;
  const float* x     = (const float*)d_in[0];
  const float* amask = (const float*)d_in[1];
  const float* eWih  = (const float*)d_in[2];
  const float* eWhh  = (const float*)d_in[3];
  const float* ebih  = (const float*)d_in[4];
  const float* ebhh  = (const float*)d_in[5];
  const float* ttW   = (const float*)d_in[6];
  const float* ttb   = (const float*)d_in[7];
  const float* polW  = (const float*)d_in[8];
  const float* polb  = (const float*)d_in[9];
  const float* c2hW  = (const float*)d_in[10];
  const float* c2hb  = (const float*)d_in[11];
  const float* pgWhh = (const float*)d_in[13];
  const float* pgbih = (const float*)d_in[14];
  const float* pgbhh = (const float*)d_in[15];
  const float* prjW  = (const float*)d_in[16];
  const float* prjb  = (const float*)d_in[17];
  const float* opW1  = (const float*)d_in[18];
  const float* opb1  = (const float*)d_in[19];
  const float* opW2  = (const float*)d_in[20];
  const float* opb2  = (const float*)d_in[21];
  const float* outW  = (const float*)d_in[22];
  const float* outB  = (const float*)d_in[23];
  float* dout = (float*)d_out;

  char* ws = (char*)d_ws;
  size_t off = 0;
  auto alloc = [&](size_t bytes)->void*{ void* p = ws + off; off += (bytes + 255) & ~(size_t)255; return p; };
  float*    xm      = (float*)   alloc(4096ULL*1024*4);
  ushort*   xmb     = (ushort*)  alloc(4096ULL*1024*2);
  ushort*   wihb    = (ushort*)  alloc(3072ULL*1024*2);
  float*    gx      = (float*)   alloc(4096ULL*3072*4);
  unsigned* hw      = (unsigned*)alloc(513ULL*8192*4);
  float*    ttpol   = (float*)   alloc(4096ULL*8*4);
  ushort*   tf      = (ushort*)  alloc(4096ULL*KP_*2);
  ushort*   w1b     = (ushort*)  alloc(8ULL*1024*KP_*2);
  ushort*   w2b     = (ushort*)  alloc(8ULL*1024*1024*2);
  ushort*   h1g     = (ushort*)  alloc(4096ULL*1024*2);
  float*    outbuf  = (float*)   alloc(4096ULL*1024*4);
  float*    pooled  = (float*)   alloc(8192*4);
  float*    csum    = (float*)   alloc(64*4);
  float*    pgh     = (float*)   alloc(5ULL*8192*4);
  float*    plog    = (float*)   alloc(256*4);
  float*    wv      = (float*)   alloc(64*4);
  float*    obias   = (float*)   alloc(8192*4);
  float*    pooled2 = (float*)   alloc(16384*4);

  // prep + weight conversions + exchange-buffer init
  k_hinit<<<32, 256, 0, stream>>>(hw);            // slot 0: value 0, tag 1
  k_prep<<<4096, 256, 0, stream>>>(x, amask, xm, xmb);
  k_cvt<<<3072, 256, 0, stream>>>(eWih, wihb, 3072*1024/4);
  k_cvt_w1<<<8192, 256, 0, stream>>>(opW1, w1b);
  k_cvt<<<8192, 256, 0, stream>>>(opW2, w2b, 8*1024*1024/4);

  // gx = x_m @ W_ih^T + b_ih
  { EpiArgs e{}; e.outf = gx; e.bias = ebih; e.ldc = TDK;
    k_gemm<0,false><<<dim3(32,24), 256, 0, stream>>>(xmb, wihb, 1024, 1024, 1024, e); }

  // GRU recurrence (persistent, 64 WGs, tag-in-data exchange)
  k_gru3<<<64, 256, 0, stream>>>(eWhh, ebhh, gx, hw);

  // token feats + concept heads + reductions
  k_tokfeat<<<4096, 256, 0, stream>>>(hw, xm, ttW, ttb, polW, polb, tf, ttpol);
  k_pooled<<<64, 128, 0, stream>>>(hw, xm, pooled);
  k_csum<<<1, 64, 0, stream>>>(ttpol, csum);

  // program generator
  k_ctx<<<32, 256, 0, stream>>>(pooled, csum, c2hW, c2hb, pgh);
  for (int t = 0; t < 4; ++t)
    k_pg<<<128, 256, 0, stream>>>(pgWhh, pgbih, pgbhh, pgh + (size_t)t*8192, pgh + (size_t)(t+1)*8192);
  k_wlogits<<<1, 256, 0, stream>>>(pgh, prjW, prjb, plog, wv);
  k_obias<<<32, 256, 0, stream>>>(wv, opb2, obias);

  // op library: per v, h1 = gelu(tf@W1^T+b1)*w[b,v] ; out += h1@W2^T (+ sum_v w*b2 at init)
  for (int v = 0; v < 8; ++v){
    EpiArgs e1{}; e1.outh = h1g; e1.bias = opb1 + v*1024; e1.wvp = wv; e1.v = v; e1.ldc = 1024;
    k_gemm<1,false><<<dim3(32,8), 256, 0, stream>>>(tf, w1b + (size_t)v*1024*KP_, KP_, KP_, KP_, e1);
    EpiArgs e2{}; e2.outf = outbuf; e2.obias = obias; e2.ldc = 1024;
    if (v == 0) k_gemm<2,true ><<<dim3(32,8), 256, 0, stream>>>(h1g, w2b + (size_t)v*1024*1024, 1024, 1024, 1024, e2);
    else        k_gemm<2,false><<<dim3(32,8), 256, 0, stream>>>(h1g, w2b + (size_t)v*1024*1024, 1024, 1024, 1024, e2);
  }

  // pooling + z + losses
  k_pool2<<<64, 128, 0, stream>>>(outbuf, pooled2);
  k_z<<<1024, 256, 0, stream>>>(pooled2, outW, outB, dout);
  k_losses<<<1, 64, 0, stream>>>(pooled2, plog, dout);
}

// Round 4
// 1689.277 us; speedup vs baseline: 4.1765x; 1.2929x over previous
//
#include <hip/hip_runtime.h>
#include <stdint.h>

// Model dims
#define D_   1024
#define T_   512
#define B_   8
#define V_   8
#define I_   1032
#define KP_  1088   // padded K for token_feats GEMM (17*64)
#define TDK  3072

typedef __attribute__((ext_vector_type(8))) short bf16x8;
typedef __attribute__((ext_vector_type(4))) float f32x4;

__device__ __forceinline__ ushort f2bf(float f){
  union{ unsigned u; float f; } c; c.f = f;
  unsigned u = c.u;
  return (ushort)((u + 0x7FFFu + ((u>>16)&1u)) >> 16);   // RNE
}
__device__ __forceinline__ float bf2f(ushort h){
  union{ unsigned u; float f; } c; c.u = ((unsigned)h) << 16; return c.f;
}
__device__ __forceinline__ float sigmoidf_(float x){ return 1.f/(1.f+__expf(-x)); }

#define WAITV(N) do{ asm volatile("s_waitcnt vmcnt(" #N ")" ::: "memory"); __builtin_amdgcn_sched_barrier(0); }while(0)

__device__ __forceinline__ void gload_lds16(const void* g, void* l){
  __builtin_amdgcn_global_load_lds((const __attribute__((address_space(1))) void*)g,
                                   (__attribute__((address_space(3))) void*)l, 16, 0, 0);
}

// ---------------- prep: x*mask -> f32 + bf16 ----------------
__global__ __launch_bounds__(256) void k_prep(const float* __restrict__ x, const float* __restrict__ mask,
                                              float* __restrict__ xm, ushort* __restrict__ xmb){
  int i = blockIdx.x*256 + threadIdx.x;          // float4 index, total 1048576
  float4 v = ((const float4*)x)[i];
  float mk = mask[i >> 8];                        // token = i*4/1024
  v.x*=mk; v.y*=mk; v.z*=mk; v.w*=mk;
  ((float4*)xm)[i] = v;
  ushort4 h; h.x=f2bf(v.x); h.y=f2bf(v.y); h.z=f2bf(v.z); h.w=f2bf(v.w);
  ((ushort4*)xmb)[i] = h;
}

// init h slot 0: value bf16(0), tag 1
__global__ __launch_bounds__(256) void k_hinit(unsigned* __restrict__ hw){
  hw[blockIdx.x*256 + threadIdx.x] = 1u;
}

// ---------------- generic f32 -> bf16 convert ----------------
__global__ __launch_bounds__(256) void k_cvt(const float* __restrict__ in, ushort* __restrict__ out, int n4){
  int i = blockIdx.x*256 + threadIdx.x;
  if (i < n4){
    float4 v = ((const float4*)in)[i];
    ushort4 h; h.x=f2bf(v.x); h.y=f2bf(v.y); h.z=f2bf(v.z); h.w=f2bf(v.w);
    ((ushort4*)out)[i] = h;
  }
}

// op_W1 (8,1024,1032) f32 -> (8,1024,1088) bf16 zero-padded
__global__ __launch_bounds__(256) void k_cvt_w1(const float* __restrict__ w1, ushort* __restrict__ w1b){
  int row = blockIdx.x;                           // 8192 rows
  const float* src = w1 + (size_t)row*I_;
  ushort* dst = w1b + (size_t)row*KP_;
  for (int c = threadIdx.x; c < KP_; c += 256){
    float v = (c < I_) ? src[c] : 0.f;
    dst[c] = f2bf(v);
  }
}

// op_W2 (8,1024,1024) f32 -> w2t (1024, 8192) bf16: w2t[d][v*1024+h] = W2[v][d][h]
__global__ __launch_bounds__(256) void k_cvt_w2t(const float* __restrict__ w2, ushort* __restrict__ w2t){
  int blk = blockIdx.x;                           // 8192 = v*1024 + d
  int v = blk >> 10, d = blk & 1023;
  const float4* src = (const float4*)(w2 + ((size_t)(v*1024 + d))*1024);
  ushort* dst = w2t + (size_t)d*8192 + v*1024;
  int i = threadIdx.x;                            // 256 threads x 4 floats
  float4 u = src[i];
  ushort4 h; h.x=f2bf(u.x); h.y=f2bf(u.y); h.z=f2bf(u.z); h.w=f2bf(u.w);
  ((ushort4*)dst)[i] = h;
}

// ---------------- bf16 MFMA GEMM (m97 structure): C(M,N) = A(M,K) @ B(N,K)^T, 128x128 tile ----------------
// global_load_lds width=16, linear LDS As/Bs[128][64], BK=64, 2 barriers per K-step.
struct EpiArgs {
  float* outf; ushort* outh;
  const float* bias; const float* wvp; const float* obias;
  int ldc;
};

template<int EPI, bool INIT>
__global__ __launch_bounds__(256) void k_gemm(const ushort* __restrict__ A, const ushort* __restrict__ Bm,
                                              int lda, int ldb, int K, EpiArgs e)
{
  __shared__ ushort As[128*64];
  __shared__ ushort Bs[128*64];
  const int tid = threadIdx.x;
  const int w = tid >> 6, l = tid & 63;
  const int wr = w >> 1, wc = w & 1;
  f32x4 acc[4][4] = {};
  const size_t arow = (size_t)(blockIdx.x*128);
  const size_t brow = (size_t)(blockIdx.y*128);
  const int lr = l >> 3, lcol = (l & 7) << 3;     // lane row-in-8 / col (ushorts)

  for (int k0 = 0; k0 < K; k0 += 64){
    __syncthreads();                              // prev compute done before overwrite
    #pragma unroll
    for (int g = 0; g < 4; ++g){
      const int chunk = (g<<2) + w;               // 0..15: 8 rows each
      const int row = (chunk<<3) + lr;
      gload_lds16(A + (arow + row)*lda + k0 + lcol, &As[chunk<<9]);
      gload_lds16(Bm + (brow + row)*ldb + k0 + lcol, &Bs[chunk<<9]);
    }
    __syncthreads();                              // compiler drains vmcnt before barrier
    #pragma unroll
    for (int kk = 0; kk < 2; ++kk){
      bf16x8 af[4], bfr[4];
      #pragma unroll
      for (int m=0;m<4;++m) af[m]  = *(const bf16x8*)&As[(wr*64 + m*16 + (l&15))*64 + kk*32 + ((l>>4)<<3)];
      #pragma unroll
      for (int n=0;n<4;++n) bfr[n] = *(const bf16x8*)&Bs[(wc*64 + n*16 + (l&15))*64 + kk*32 + ((l>>4)<<3)];
      #pragma unroll
      for (int m=0;m<4;++m)
        #pragma unroll
        for (int n=0;n<4;++n)
          acc[m][n] = __builtin_amdgcn_mfma_f32_16x16x32_bf16(af[m], bfr[n], acc[m][n], 0, 0, 0);
    }
  }
  // C/D layout (m89): col = lane&15, row = (lane>>4)*4 + reg
  const int row0 = blockIdx.x*128 + wr*64 + ((l>>4)<<2);
  const int col0 = blockIdx.y*128 + wc*64 + (l&15);
  #pragma unroll
  for (int m=0;m<4;++m){
    #pragma unroll
    for (int n=0;n<4;++n){
      f32x4 a = acc[m][n];
      int col = col0 + n*16;
      #pragma unroll
      for (int q=0;q<4;++q){
        int row = row0 + m*16 + q;
        float val = a[q];
        if constexpr (EPI==0){                 // gx: + per-col bias (enc_bih), f32 out
          e.outf[(size_t)row*e.ldc + col] = val + e.bias[col];
        } else if constexpr (EPI==1){          // h1 fused-V: gelu(acc+b1[col])*w[b, col>>10] -> bf16
          float xg = val + e.bias[col];
          float g = 0.5f*xg*(1.0f + erff(xg*0.70710678118f));
          e.outh[(size_t)row*e.ldc + col] = f2bf(g * e.wvp[(row>>9)*V_ + (col>>10)]);
        } else {                               // out fused-K: + weighted b2 bias
          size_t idx = (size_t)row*e.ldc + col;
          float prev = INIT ? e.obias[((row>>9)<<10) + col] : e.outf[idx];
          e.outf[idx] = prev + val;
        }
      }
    }
  }
}

// ---------------- persistent GRU recurrence v4: coalesced wave-local poll + LDS redistribute ----------------
// 64 WGs; WG c owns dims [16c,16c+16). Tag-in-data words: (bf16(h)<<16)|(slot+1).
// Wave w polls only its K-quarter with 8 fully-coalesced 1KB loads; selective per-row retry;
// tag-stripped values bounce through wave-private LDS into MFMA fragment layout (no barrier).
// Gates spread over all 4 waves (2 batches each); Red double-buffered -> ONE syncthreads/step.
__global__ __launch_bounds__(256, 1) void k_gru4(const float* __restrict__ whh, const float* __restrict__ bhh,
                                                 const float* __restrict__ gx, unsigned* __restrict__ hw)
{
  __shared__ ushort Hld[4][8][264];               // [wave][batch-row][256 quarter-cols + 8 pad]
  __shared__ float Red[2][1536];                  // double-buffered [4 waves][3 gates][128]
  const int tid = threadIdx.x, c = blockIdx.x;
  const int w = tid >> 6, l = tid & 63;
  const int ar = l & 15, kg = (l >> 4) << 3;

  // hoist W_hh fragments: Bf[g][s] = bf16(whh[g*1024 + c*16 + ar][w*256 + s*32 + kg .. +7])
  bf16x8 Bf[3][8];
  #pragma unroll
  for (int g = 0; g < 3; ++g){
    #pragma unroll
    for (int s = 0; s < 8; ++s){
      const float* src = whh + ((size_t)((g<<10) + (c<<4) + ar))*1024 + (w<<8) + (s<<5) + kg;
      float4 u0 = *(const float4*)src;
      float4 u1 = *(const float4*)(src + 4);
      bf16x8 f;
      f[0]=(short)f2bf(u0.x); f[1]=(short)f2bf(u0.y); f[2]=(short)f2bf(u0.z); f[3]=(short)f2bf(u0.w);
      f[4]=(short)f2bf(u1.x); f[5]=(short)f2bf(u1.y); f[6]=(short)f2bf(u1.z); f[7]=(short)f2bf(u1.w);
      Bf[g][s] = f;
    }
  }
  // producer mapping (lanes l<32 of each wave): batch pb, dim-in-16 pi
  const int pb = (w << 1) + ((l >> 4) & 1);
  const int pi = l & 15;
  const int dg = (c << 4) + pi;
  const float bhr = bhh[dg], bhz = bhh[1024 + dg], bhn = bhh[2048 + dg];
  float hp = 0.f;
  __syncthreads();

  for (int t = 0; t < 512; ++t){
    // gx loads for this step (l<32; consumed after the barrier — fully overlapped)
    float xr, xz, xn;
    if (l < 32){
      const float* g0 = gx + ((size_t)(pb*512 + t))*TDK + dg;
      asm volatile("global_load_dword %0, %1, off" : "=v"(xr) : "v"(g0)        : "memory");
      asm volatile("global_load_dword %0, %1, off" : "=v"(xz) : "v"(g0 + 1024) : "memory");
      asm volatile("global_load_dword %0, %1, off" : "=v"(xn) : "v"(g0 + 2048) : "memory");
    }
    // coalesced wave-local poll: row j (batch), lane covers dwords l*4..l*4+4 of this wave's quarter
    uint4 rw[8];
    unsigned ok = 0;
    const unsigned tagv = (unsigned)(t + 1);
    const unsigned* qb = hw + ((size_t)t << 13) + (w << 8) + (l << 2);
    while (true){
      #pragma unroll
      for (int j = 0; j < 8; ++j){
        if (!(ok & (1u << j))){
          asm volatile("global_load_dwordx4 %0, %1, off sc0 sc1" : "=v"(rw[j]) : "v"(qb + (j << 10)) : "memory");
        }
      }
      WAITV(0);
      #pragma unroll
      for (int j = 0; j < 8; ++j){
        if (!(ok & (1u << j))){
          unsigned m = (rw[j].x ^ tagv) | (rw[j].y ^ tagv) | (rw[j].z ^ tagv) | (rw[j].w ^ tagv);
          if ((m & 0xFFFFu) == 0u) ok |= (1u << j);
        }
      }
      if (__all(ok == 0xFFu)) break;
    }
    // strip tags -> bf16 pairs -> wave-private LDS (ds_write_b64); no barrier (same-wave lgkmcnt)
    #pragma unroll
    for (int j = 0; j < 8; ++j){
      unsigned d0 = __builtin_amdgcn_perm(rw[j].y, rw[j].x, 0x07060302u);
      unsigned d1 = __builtin_amdgcn_perm(rw[j].w, rw[j].z, 0x07060302u);
      union { unsigned u[2]; unsigned long long ull; } cv; cv.u[0]=d0; cv.u[1]=d1;
      *(unsigned long long*)&Hld[w][j][l<<2] = cv.ull;
    }
    // fragments from LDS + MFMA (lanes ar>=8 duplicate row ar&7 -> C rows 8..15 garbage, never read)
    f32x4 ac0 = {0.f,0.f,0.f,0.f}, ac1 = {0.f,0.f,0.f,0.f}, ac2 = {0.f,0.f,0.f,0.f};
    #pragma unroll
    for (int s = 0; s < 8; ++s){
      bf16x8 af = *(const bf16x8*)&Hld[w][ar & 7][(s << 5) + kg];
      ac0 = __builtin_amdgcn_mfma_f32_16x16x32_bf16(af, Bf[0][s], ac0, 0, 0, 0);
      ac1 = __builtin_amdgcn_mfma_f32_16x16x32_bf16(af, Bf[1][s], ac1, 0, 0, 0);
      ac2 = __builtin_amdgcn_mfma_f32_16x16x32_bf16(af, Bf[2][s], ac2, 0, 0, 0);
    }
    const int cur = t & 1;
    if (l < 32){
      *(f32x4*)(&Red[cur][(w*3+0)*128 + l*4]) = ac0;
      *(f32x4*)(&Red[cur][(w*3+1)*128 + l*4]) = ac1;
      *(f32x4*)(&Red[cur][(w*3+2)*128 + l*4]) = ac2;
    }
    __syncthreads();                              // the ONE barrier per step
    if (l < 32){
      const int idx = (((pb>>2)<<4) | pi)*4 + (pb & 3);
      const float* R = Red[cur];
      float ghr = R[idx]       + R[384 + idx]  + R[768 + idx]  + R[1152 + idx];
      float ghz = R[128 + idx] + R[512 + idx]  + R[896 + idx]  + R[1280 + idx];
      float ghn = R[256 + idx] + R[640 + idx]  + R[1024 + idx] + R[1408 + idx];
      float r  = sigmoidf_(xr + ghr + bhr);
      float z  = sigmoidf_(xz + ghz + bhz);
      float nn = tanhf(xn + r*(ghn + bhn));
      hp = (1.f - z)*nn + z*hp;                   // f32 carry in register
      unsigned word = (((unsigned)f2bf(hp)) << 16) | (unsigned)(t + 2);
      unsigned* hdst = hw + ((size_t)(t+1) << 13) + (pb << 10) + dg;
      asm volatile("global_store_dword %0, %1, off sc0 sc1" :: "v"(hdst), "v"(word) : "memory");
    }
  }
}

// ---------------- token feats: xe = gru+xm ; tt/pol heads ; build padded bf16 token_feats ----------------
__global__ __launch_bounds__(256) void k_tokfeat(const unsigned* __restrict__ hw, const float* __restrict__ xm,
                                                 const float* __restrict__ ttW, const float* __restrict__ ttb,
                                                 const float* __restrict__ polW, const float* __restrict__ polb,
                                                 ushort* __restrict__ tf, float* __restrict__ ttpol){
  __shared__ float xe[1024];
  const int tok = blockIdx.x;              // b*512 + t
  const int b = tok >> 9, t = tok & 511;
  const int tid = threadIdx.x;
  uint4 hv4 = *((const uint4*)(hw + ((size_t)(t+1) << 13) + ((size_t)b << 10)) + tid);
  float4 xv = ((const float4*)(xm + (size_t)tok*1024))[tid];
  float4 ev;
  ev.x = bf2f((ushort)(hv4.x >> 16)) + xv.x;
  ev.y = bf2f((ushort)(hv4.y >> 16)) + xv.y;
  ev.z = bf2f((ushort)(hv4.z >> 16)) + xv.z;
  ev.w = bf2f((ushort)(hv4.w >> 16)) + xv.w;
  *(float4*)&xe[tid*4] = ev;
  ushort4 eb; eb.x=f2bf(ev.x); eb.y=f2bf(ev.y); eb.z=f2bf(ev.z); eb.w=f2bf(ev.w);
  *(ushort4*)&tf[(size_t)tok*KP_ + tid*4] = eb;
  __syncthreads();
  const int j = tid >> 5, ln = tid & 31;
  const float* Wr = (j < 6) ? (ttW + j*1024) : (polW + (j-6)*1024);
  float acc = 0.f;
  for (int k = ln; k < 1024; k += 32) acc += xe[k]*Wr[k];
  #pragma unroll
  for (int m=16; m>=1; m>>=1) acc += __shfl_xor(acc, m, 32);
  if (ln == 0){
    float val = acc + ((j<6)? ttb[j] : polb[j-6]);
    ttpol[(size_t)tok*8 + j] = val;
    tf[(size_t)tok*KP_ + 1024 + j] = f2bf(val);
  }
  if (tid < 56) tf[(size_t)tok*KP_ + 1032 + tid] = 0;   // K padding
}

// pooled[b][d] = mean_t xe
__global__ __launch_bounds__(128) void k_pooled(const unsigned* __restrict__ hw, const float* __restrict__ xm,
                                                float* __restrict__ pooled){
  const int b = blockIdx.x >> 3;
  const int d = ((blockIdx.x & 7) << 7) + threadIdx.x;
  float s = 0.f;
  for (int t=0; t<512; ++t)
    s += bf2f((ushort)(hw[((size_t)(t+1) << 13) + (b << 10) + d] >> 16)) + xm[((size_t)(b*512+t)<<10) + d];
  pooled[(b<<10)+d] = s * (1.f/512.f);
}

__global__ __launch_bounds__(64) void k_csum(const float* __restrict__ ttpol, float* __restrict__ csum){
  const int b = threadIdx.x >> 3, j = threadIdx.x & 7;
  float s = 0.f;
  for (int t=0; t<512; ++t) s += ttpol[((size_t)(b*512+t)<<3) + j];
  csum[threadIdx.x] = s * (1.f/512.f);
}

// pg_h0 = context @ c2h_W^T + c2h_b
__global__ __launch_bounds__(256) void k_ctx(const float* __restrict__ pooled, const float* __restrict__ csum,
                                             const float* __restrict__ c2hW, const float* __restrict__ c2hb,
                                             float* __restrict__ pgh0){
  const int i = blockIdx.x*256 + threadIdx.x;   // 8192
  const int b = i >> 10, d = i & 1023;
  const float* wr = c2hW + (size_t)d*I_;
  const float* pb = pooled + (b<<10);
  float acc = c2hb[d];
  for (int k=0; k<1024; ++k) acc += pb[k]*wr[k];
  #pragma unroll
  for (int k=0; k<8; ++k) acc += csum[b*8+k]*wr[1024+k];
  pgh0[i] = acc;
}

// one PG GRU step (rnn_in = 0 so gx = pg_bih)
__global__ __launch_bounds__(256) void k_pg(const float* __restrict__ whh, const float* __restrict__ bih,
                                            const float* __restrict__ bhh, const float* __restrict__ hin,
                                            float* __restrict__ hout){
  __shared__ float sh[8][1024];
  const int tid = threadIdx.x;
  for (int f = tid; f < 2048; f += 256) ((float4*)&sh[0][0])[f] = ((const float4*)hin)[f];
  __syncthreads();
  const int d = blockIdx.x*8 + (tid>>5), ln = tid & 31;
  const float* wr = whh + (size_t)d*1024;
  const float* wz = whh + (size_t)(1024+d)*1024;
  const float* wn = whh + (size_t)(2048+d)*1024;
  float ar[8]={0,0,0,0,0,0,0,0}, az[8]={0,0,0,0,0,0,0,0}, an[8]={0,0,0,0,0,0,0,0};
  for (int k = ln; k < 1024; k += 32){
    float r_=wr[k], z_=wz[k], n_=wn[k];
    #pragma unroll
    for (int b=0;b<8;++b){ float h = sh[b][k]; ar[b]+=h*r_; az[b]+=h*z_; an[b]+=h*n_; }
  }
  #pragma unroll
  for (int m=16; m>=1; m>>=1){
    #pragma unroll
    for (int b=0;b<8;++b){ ar[b]+=__shfl_xor(ar[b],m,32); az[b]+=__shfl_xor(az[b],m,32); an[b]+=__shfl_xor(an[b],m,32); }
  }
  if (ln == 0){
    float xr=bih[d], xz=bih[1024+d], xn=bih[2048+d];
    float br=bhh[d], bz=bhh[1024+d], bn=bhh[2048+d];
    #pragma unroll
    for (int b=0;b<8;++b){
      float r = sigmoidf_(xr + ar[b] + br);
      float z = sigmoidf_(xz + az[b] + bz);
      float nn = tanhf(xn + r*(an[b] + bn));
      hout[(b<<10)+d] = (1.f - z)*nn + z*sh[b][d];
    }
  }
}

// program logits + softmax + mean over L -> w[b][v]
__global__ __launch_bounds__(256) void k_wlogits(const float* __restrict__ pgh, const float* __restrict__ prjW,
                                                 const float* __restrict__ prjb, float* __restrict__ plog,
                                                 float* __restrict__ wv){
  __shared__ float lg[256];
  __shared__ float sm[256];
  const int tid = threadIdx.x;
  const int b = tid>>5, li = (tid>>3)&3, v = tid&7;
  const float* h = pgh + (size_t)(li+1)*8192 + (b<<10);
  const float* pw = prjW + (v<<10);
  float acc = prjb[v];
  for (int k=0;k<1024;++k) acc += h[k]*pw[k];
  lg[tid] = acc;         // tid == b*32 + li*8 + v
  plog[tid] = acc;
  __syncthreads();
  if (tid < 32){
    const int bb = tid>>2, ll = tid&3;
    const float* row = &lg[bb*32 + ll*8];
    float mx = row[0];
    #pragma unroll
    for (int u=1;u<8;++u) mx = fmaxf(mx, row[u]);
    float e[8], s=0.f;
    #pragma unroll
    for (int u=0;u<8;++u){ e[u]=__expf(row[u]-mx); s+=e[u]; }
    #pragma unroll
    for (int u=0;u<8;++u) sm[(bb*4+ll)*8+u] = e[u]/s;
  }
  __syncthreads();
  if (tid < 64){
    const int bb = tid>>3, u = tid&7;
    float s = sm[(bb*4+0)*8+u] + sm[(bb*4+1)*8+u] + sm[(bb*4+2)*8+u] + sm[(bb*4+3)*8+u];
    wv[bb*8+u] = 0.25f*s;
  }
}

__global__ __launch_bounds__(256) void k_obias(const float* __restrict__ wv, const float* __restrict__ opb2,
                                               float* __restrict__ obias){
  const int i = blockIdx.x*256 + threadIdx.x;   // 8192
  const int b = i>>10, d = i&1023;
  float s = 0.f;
  #pragma unroll
  for (int v=0; v<8; ++v) s += wv[b*8+v]*opb2[(v<<10)+d];
  obias[i] = s;
}

// pooled2 = [max_t out | mean_t out]
__global__ __launch_bounds__(128) void k_pool2(const float* __restrict__ outb, float* __restrict__ pooled2){
  const int b = blockIdx.x >> 3;
  const int col = ((blockIdx.x & 7) << 7) + threadIdx.x;
  float mx = -3.4e38f, sm = 0.f;
  for (int t=0; t<512; ++t){
    float v = outb[((size_t)(b*512+t)<<10) + col];
    mx = fmaxf(mx, v); sm += v;
  }
  pooled2[((size_t)b<<11) + col] = mx;
  pooled2[((size_t)b<<11) + 1024 + col] = sm*(1.f/512.f);
}

// z = pooled2 @ out_W^T + out_b  -> d_out[0..8191]
__global__ __launch_bounds__(256) void k_z(const float* __restrict__ pooled2, const float* __restrict__ outW,
                                           const float* __restrict__ outBias, float* __restrict__ dout){
  __shared__ float p2[2048];
  const int o = blockIdx.x << 3;
  const int b = o >> 10, dbase = o & 1023;
  for (int f = threadIdx.x; f < 512; f += 256)
    ((float4*)p2)[f] = ((const float4*)(pooled2 + ((size_t)b<<11)))[f];
  __syncthreads();
  const int g = threadIdx.x >> 5, ln = threadIdx.x & 31;
  const int d = dbase + g;
  const float* wr = outW + ((size_t)d << 11);
  float acc = 0.f;
  for (int k = ln; k < 2048; k += 32) acc += p2[k]*wr[k];
  #pragma unroll
  for (int m=16; m>=1; m>>=1) acc += __shfl_xor(acc, m, 32);
  if (ln == 0) dout[(b<<10) + d] = acc + outBias[d];
}

// reuse + contrastive losses (exact f32)
__global__ __launch_bounds__(64) void k_losses(const float* __restrict__ p2g, const float* __restrict__ plog,
                                               float* __restrict__ dout){
  __shared__ float p2n[8], sq[8], pn[8];
  const int l = threadIdx.x;
  { const int b=l>>3, p=l&7; float s=0.f;
    const float* row = p2g + ((size_t)b<<11) + (p<<8);
    for (int k=0;k<256;++k){ float v=row[k]; s += v*v; }
    s += __shfl_xor(s,4,8); s += __shfl_xor(s,2,8); s += __shfl_xor(s,1,8);
    if (p==0) p2n[b] = fmaxf(sqrtf(s), 1e-12f);
  }
  if (l < 8){
    float s=0.f;
    #pragma unroll
    for (int k=0;k<32;++k){ float v=plog[l*32+k]; s+=v*v; }
    sq[l]=s; pn[l]=fmaxf(sqrtf(s),1e-12f);
  }
  __syncthreads();
  const int i=l>>3, j=l&7;
  const float* ri = p2g + ((size_t)i<<11);
  const float* rj = p2g + ((size_t)j<<11);
  float dot=0.f; for (int k=0;k<2048;++k) dot += ri[k]*rj[k];
  float sim = dot/(p2n[i]*p2n[j]);
  float pd=0.f;
  #pragma unroll
  for (int k=0;k<32;++k) pd += plog[i*32+k]*plog[j*32+k];
  float d2 = fmaxf(sq[i]+sq[j]-2.f*pd, 0.f);
  float dist = (d2>0.f)? sqrtf(d2) : 0.f;
  float psim = pd/(pn[i]*pn[j]);
  float pos = (sim>0.7f)?1.f:0.f, neg = (sim<0.7f)?1.f:0.f;
  float rs = sim*dist, ps=(1.f-psim)*pos, ns=fmaxf(psim-0.5f,0.f)*neg, pc=pos, nc=neg;
  #pragma unroll
  for (int m=32; m>=1; m>>=1){
    rs+=__shfl_xor(rs,m); ps+=__shfl_xor(ps,m); ns+=__shfl_xor(ns,m);
    pc+=__shfl_xor(pc,m); nc+=__shfl_xor(nc,m);
  }
  if (l==0){ dout[8192]=rs*(1.f/64.f); dout[8193]=(ps+ns)/(pc+nc+1e-6f); }
}

// ============================ host ============================
extern "C" void kernel_launch(void* const* d_in, const int* in_sizes, int n_in,
                              void* d_out, int out_size, void* d_ws, size_t ws_size,
                              hipStream_t stream) {
  (void)in_sizes; (void)n_in; (void)out_size; (void)ws_size;
  const float* x     = (const float*)d_in[0];
  const float* amask = (const float*)d_in[1];
  const float* eWih  = (const float*)d_in[2];
  const float* eWhh  = (const float*)d_in[3];
  const float* ebih  = (const float*)d_in[4];
  const float* ebhh  = (const float*)d_in[5];
  const float* ttW   = (const float*)d_in[6];
  const float* ttb   = (const float*)d_in[7];
  const float* polW  = (const float*)d_in[8];
  const float* polb  = (const float*)d_in[9];
  const float* c2hW  = (const float*)d_in[10];
  const float* c2hb  = (const float*)d_in[11];
  const float* pgWhh = (const float*)d_in[13];
  const float* pgbih = (const float*)d_in[14];
  const float* pgbhh = (const float*)d_in[15];
  const float* prjW  = (const float*)d_in[16];
  const float* prjb  = (const float*)d_in[17];
  const float* opW1  = (const float*)d_in[18];
  const float* opb1  = (const float*)d_in[19];
  const float* opW2  = (const float*)d_in[20];
  const float* opb2  = (const float*)d_in[21];
  const float* outW  = (const float*)d_in[22];
  const float* outB  = (const float*)d_in[23];
  float* dout = (float*)d_out;

  char* ws = (char*)d_ws;
  size_t off = 0;
  auto alloc = [&](size_t bytes)->void*{ void* p = ws + off; off += (bytes + 255) & ~(size_t)255; return p; };
  // R region (64MB): xm (16MB) + gx (48MB), later reused as h1g (4096 x 8192 bf16 = 64MB)
  char*     R       = (char*)   alloc(64ULL*1024*1024);
  float*    xm      = (float*)  R;
  float*    gx      = (float*) (R + 16ULL*1024*1024);
  ushort*   h1g     = (ushort*) R;
  ushort*   xmb     = (ushort*)  alloc(4096ULL*1024*2);
  ushort*   wihb    = (ushort*)  alloc(3072ULL*1024*2);
  unsigned* hw      = (unsigned*)alloc(513ULL*8192*4);
  float*    ttpol   = (float*)   alloc(4096ULL*8*4);
  ushort*   tf      = (ushort*)  alloc(4096ULL*KP_*2);
  ushort*   w1b     = (ushort*)  alloc(8ULL*1024*KP_*2);
  ushort*   w2t     = (ushort*)  alloc(1024ULL*8192*2);
  float*    outbuf  = (float*)   alloc(4096ULL*1024*4);
  float*    pooled  = (float*)   alloc(8192*4);
  float*    csum    = (float*)   alloc(64*4);
  float*    pgh     = (float*)   alloc(5ULL*8192*4);
  float*    plog    = (float*)   alloc(256*4);
  float*    wv      = (float*)   alloc(64*4);
  float*    obias   = (float*)   alloc(8192*4);
  float*    pooled2 = (float*)   alloc(16384*4);

  // prep + weight conversions + exchange-buffer init
  k_hinit<<<32, 256, 0, stream>>>(hw);            // slot 0: value 0, tag 1
  k_prep<<<4096, 256, 0, stream>>>(x, amask, xm, xmb);
  k_cvt<<<3072, 256, 0, stream>>>(eWih, wihb, 3072*1024/4);
  k_cvt_w1<<<8192, 256, 0, stream>>>(opW1, w1b);
  k_cvt_w2t<<<8192, 256, 0, stream>>>(opW2, w2t);

  // gx = x_m @ W_ih^T + b_ih
  { EpiArgs e{}; e.outf = gx; e.bias = ebih; e.ldc = TDK;
    k_gemm<0,false><<<dim3(32,24), 256, 0, stream>>>(xmb, wihb, 1024, 1024, 1024, e); }

  // GRU recurrence (persistent, 64 WGs, coalesced tag-in-data exchange)
  k_gru4<<<64, 256, 0, stream>>>(eWhh, ebhh, gx, hw);

  // token feats + concept heads + reductions (xm/gx still live here)
  k_tokfeat<<<4096, 256, 0, stream>>>(hw, xm, ttW, ttb, polW, polb, tf, ttpol);
  k_pooled<<<64, 128, 0, stream>>>(hw, xm, pooled);
  k_csum<<<1, 64, 0, stream>>>(ttpol, csum);

  // program generator
  k_ctx<<<32, 256, 0, stream>>>(pooled, csum, c2hW, c2hb, pgh);
  for (int t = 0; t < 4; ++t)
    k_pg<<<128, 256, 0, stream>>>(pgWhh, pgbih, pgbhh, pgh + (size_t)t*8192, pgh + (size_t)(t+1)*8192);
  k_wlogits<<<1, 256, 0, stream>>>(pgh, prjW, prjb, plog, wv);
  k_obias<<<32, 256, 0, stream>>>(wv, opb2, obias);

  // op library fused: h1 (one dispatch, N=8192 over v) then out (one dispatch, K=8192 over v)
  // h1g overwrites xm+gx region — all consumers of xm/gx have completed.
  { EpiArgs e{}; e.outh = h1g; e.bias = opb1; e.wvp = wv; e.ldc = 8192;
    k_gemm<1,false><<<dim3(32,64), 256, 0, stream>>>(tf, w1b, KP_, KP_, KP_, e); }
  { EpiArgs e{}; e.outf = outbuf; e.obias = obias; e.ldc = 1024;
    k_gemm<2,true><<<dim3(32,8), 256, 0, stream>>>(h1g, w2t, 8192, 8192, 8192, e); }

  // pooling + z + losses
  k_pool2<<<64, 128, 0, stream>>>(outbuf, pooled2);
  k_z<<<1024, 256, 0, stream>>>(pooled2, outW, outB, dout);
  k_losses<<<1, 64, 0, stream>>>(pooled2, plog, dout);
}

// Round 5
// 1619.958 us; speedup vs baseline: 4.3552x; 1.0428x over previous
//
#include <hip/hip_runtime.h>
#include <stdint.h>

// Model dims
#define D_   1024
#define T_   512
#define B_   8
#define V_   8
#define I_   1032
#define KP_  1088   // padded K for token_feats GEMM (17*64)
#define TDK  3072
#define NGRU 64
#define NHELP 192

typedef __attribute__((ext_vector_type(8))) short bf16x8;
typedef __attribute__((ext_vector_type(4))) float f32x4;

__device__ __forceinline__ ushort f2bf(float f){
  union{ unsigned u; float f; } c; c.f = f;
  unsigned u = c.u;
  return (ushort)((u + 0x7FFFu + ((u>>16)&1u)) >> 16);   // RNE
}
__device__ __forceinline__ float bf2f(ushort h){
  union{ unsigned u; float f; } c; c.u = ((unsigned)h) << 16; return c.f;
}
__device__ __forceinline__ float sigmoidf_(float x){ return 1.f/(1.f+__expf(-x)); }

#define WAITV0 do{ asm volatile("s_waitcnt vmcnt(0)" ::: "memory"); __builtin_amdgcn_sched_barrier(0); }while(0)
#define WAITV3 do{ asm volatile("s_waitcnt vmcnt(3)" ::: "memory"); __builtin_amdgcn_sched_barrier(0); }while(0)

__device__ __forceinline__ void gload_lds16(const void* g, void* l){
  __builtin_amdgcn_global_load_lds((const __attribute__((address_space(1))) void*)g,
                                   (__attribute__((address_space(3))) void*)l, 16, 0, 0);
}

// ---------------- prep: x*mask -> f32 + bf16 ----------------
__global__ __launch_bounds__(256) void k_prep(const float* __restrict__ x, const float* __restrict__ mask,
                                              float* __restrict__ xm, ushort* __restrict__ xmb){
  int i = blockIdx.x*256 + threadIdx.x;          // float4 index, total 1048576
  float4 v = ((const float4*)x)[i];
  float mk = mask[i >> 8];                        // token = i*4/1024
  v.x*=mk; v.y*=mk; v.z*=mk; v.w*=mk;
  ((float4*)xm)[i] = v;
  ushort4 h; h.x=f2bf(v.x); h.y=f2bf(v.y); h.z=f2bf(v.z); h.w=f2bf(v.w);
  ((ushort4*)xmb)[i] = h;
}

// init h slot 0: value bf16(0), tag 1
__global__ __launch_bounds__(256) void k_hinit(unsigned* __restrict__ hw){
  hw[blockIdx.x*256 + threadIdx.x] = 1u;
}

// ---------------- generic f32 -> bf16 convert ----------------
__global__ __launch_bounds__(256) void k_cvt(const float* __restrict__ in, ushort* __restrict__ out, int n4){
  int i = blockIdx.x*256 + threadIdx.x;
  if (i < n4){
    float4 v = ((const float4*)in)[i];
    ushort4 h; h.x=f2bf(v.x); h.y=f2bf(v.y); h.z=f2bf(v.z); h.w=f2bf(v.w);
    ((ushort4*)out)[i] = h;
  }
}

// ---------------- bf16 MFMA GEMM (m97 structure): C(M,N) = A(M,K) @ B(N,K)^T, 128x128 tile ----------------
struct EpiArgs {
  float* outf; ushort* outh;
  const float* bias; const float* wvp; const float* obias;
  int ldc;
};

template<int EPI, bool INIT>
__global__ __launch_bounds__(256) void k_gemm(const ushort* __restrict__ A, const ushort* __restrict__ Bm,
                                              int lda, int ldb, int K, EpiArgs e)
{
  __shared__ ushort As[128*64];
  __shared__ ushort Bs[128*64];
  const int tid = threadIdx.x;
  const int w = tid >> 6, l = tid & 63;
  const int wr = w >> 1, wc = w & 1;
  f32x4 acc[4][4] = {};
  const size_t arow = (size_t)(blockIdx.x*128);
  const size_t brow = (size_t)(blockIdx.y*128);
  const int lr = l >> 3, lcol = (l & 7) << 3;

  for (int k0 = 0; k0 < K; k0 += 64){
    __syncthreads();
    #pragma unroll
    for (int g = 0; g < 4; ++g){
      const int chunk = (g<<2) + w;
      const int row = (chunk<<3) + lr;
      gload_lds16(A + (arow + row)*lda + k0 + lcol, &As[chunk<<9]);
      gload_lds16(Bm + (brow + row)*ldb + k0 + lcol, &Bs[chunk<<9]);
    }
    __syncthreads();
    #pragma unroll
    for (int kk = 0; kk < 2; ++kk){
      bf16x8 af[4], bfr[4];
      #pragma unroll
      for (int m=0;m<4;++m) af[m]  = *(const bf16x8*)&As[(wr*64 + m*16 + (l&15))*64 + kk*32 + ((l>>4)<<3)];
      #pragma unroll
      for (int n=0;n<4;++n) bfr[n] = *(const bf16x8*)&Bs[(wc*64 + n*16 + (l&15))*64 + kk*32 + ((l>>4)<<3)];
      #pragma unroll
      for (int m=0;m<4;++m)
        #pragma unroll
        for (int n=0;n<4;++n)
          acc[m][n] = __builtin_amdgcn_mfma_f32_16x16x32_bf16(af[m], bfr[n], acc[m][n], 0, 0, 0);
    }
  }
  const int row0 = blockIdx.x*128 + wr*64 + ((l>>4)<<2);
  const int col0 = blockIdx.y*128 + wc*64 + (l&15);
  #pragma unroll
  for (int m=0;m<4;++m){
    #pragma unroll
    for (int n=0;n<4;++n){
      f32x4 a = acc[m][n];
      int col = col0 + n*16;
      #pragma unroll
      for (int q=0;q<4;++q){
        int row = row0 + m*16 + q;
        float val = a[q];
        if constexpr (EPI==1){                 // h1 fused-V: gelu(acc+b1[col])*w[b, col>>10] -> bf16
          float xg = val + e.bias[col];
          float g = 0.5f*xg*(1.0f + erff(xg*0.70710678118f));
          e.outh[(size_t)row*e.ldc + col] = f2bf(g * e.wvp[(row>>9)*V_ + (col>>10)]);
        } else {                               // out fused-K: + weighted b2 bias
          size_t idx = (size_t)row*e.ldc + col;
          float prev = INIT ? e.obias[((row>>9)<<10) + col] : e.outf[idx];
          e.outf[idx] = prev + val;
        }
      }
    }
  }
}

// ================= MEGA KERNEL =================
// WGs 0..63: GRU recurrence (tag-in-data exchange, gx prefetch one step ahead,
//            per-128-step gx gating on done-flags, watermark publish by WG0).
// WGs 64..255 (helpers): (1) gx GEMM tiles in t-priority order (sc0sc1 stores + done flags),
//            (2) w1b / w2t weight conversions, (3) xsum (WGs 64..95), (4) tokfeat per token.
__global__ __launch_bounds__(256, 1) void k_mega(
    const float* __restrict__ whh, const float* __restrict__ bhh,
    const ushort* __restrict__ xmb, const ushort* __restrict__ wihb,
    const float* __restrict__ ebih, float* __restrict__ gx,
    unsigned* __restrict__ hw, const float* __restrict__ xm,
    const float* __restrict__ ttW, const float* __restrict__ ttb,
    const float* __restrict__ polW, const float* __restrict__ polb,
    ushort* __restrict__ tf, float* __restrict__ ttpol,
    const float* __restrict__ opW1, ushort* __restrict__ w1b,
    const float* __restrict__ opW2, ushort* __restrict__ w2t,
    float* __restrict__ hsum, float* __restrict__ xsum,
    int* __restrict__ done, int* __restrict__ wm)
{
  __shared__ char smem[32768];
  const int tid = threadIdx.x;
  const int w = tid >> 6, l = tid & 63;

  if (blockIdx.x < NGRU){
    // ---------------- GRU path ----------------
    const int c = blockIdx.x;
    const int ar = l & 15, kg = (l >> 4) << 3;
    ushort (*Hld)[264] = (ushort (*)[264])smem;          // [4*8][264]
    float* Red = (float*)(smem + 4*8*264*2);             // [2][1536]

    bf16x8 Bf[3][8];
    #pragma unroll
    for (int g = 0; g < 3; ++g){
      #pragma unroll
      for (int s = 0; s < 8; ++s){
        const float* src = whh + ((size_t)((g<<10) + (c<<4) + ar))*1024 + (w<<8) + (s<<5) + kg;
        float4 u0 = *(const float4*)src;
        float4 u1 = *(const float4*)(src + 4);
        bf16x8 f;
        f[0]=(short)f2bf(u0.x); f[1]=(short)f2bf(u0.y); f[2]=(short)f2bf(u0.z); f[3]=(short)f2bf(u0.w);
        f[4]=(short)f2bf(u1.x); f[5]=(short)f2bf(u1.y); f[6]=(short)f2bf(u1.z); f[7]=(short)f2bf(u1.w);
        Bf[g][s] = f;
      }
    }
    const int pb = (w << 1) + ((l >> 4) & 1);
    const int pi = l & 15;
    const int dg = (c << 4) + pi;
    const float bhr = bhh[dg], bhz = bhh[1024 + dg], bhn = bhh[2048 + dg];
    float hp = 0.f, hacc = 0.f;
    __syncthreads();

    // gate block 0 (gx tiles for t<128)
    {
      const int* dp = done + l*3;
      int f0, f1, f2;
      while (true){
        asm volatile("global_load_dword %0, %1, off sc0 sc1" : "=v"(f0) : "v"(dp)   : "memory");
        asm volatile("global_load_dword %0, %1, off sc0 sc1" : "=v"(f1) : "v"(dp+1) : "memory");
        asm volatile("global_load_dword %0, %1, off sc0 sc1" : "=v"(f2) : "v"(dp+2) : "memory");
        WAITV0;
        if (__all((f0 & f1 & f2) == 1)) break;
        __builtin_amdgcn_s_sleep(4);
      }
    }
    __syncthreads();
    // prologue gx(0)
    float xr, xz, xn, nxr, nxz, nxn;
    if (l < 32){
      const float* g0 = gx + ((size_t)(pb*512))*TDK + dg;
      asm volatile("global_load_dword %0, %1, off sc0 sc1" : "=v"(xr) : "v"(g0)        : "memory");
      asm volatile("global_load_dword %0, %1, off sc0 sc1" : "=v"(xz) : "v"(g0 + 1024) : "memory");
      asm volatile("global_load_dword %0, %1, off sc0 sc1" : "=v"(xn) : "v"(g0 + 2048) : "memory");
    }
    WAITV0;

    for (int t = 0; t < 512; ++t){
      if ((t & 127) == 0 && t){
        const int tq = t >> 7;
        const int* dp = done + tq*192 + l*3;
        int f0, f1, f2;
        while (true){
          asm volatile("global_load_dword %0, %1, off sc0 sc1" : "=v"(f0) : "v"(dp)   : "memory");
          asm volatile("global_load_dword %0, %1, off sc0 sc1" : "=v"(f1) : "v"(dp+1) : "memory");
          asm volatile("global_load_dword %0, %1, off sc0 sc1" : "=v"(f2) : "v"(dp+2) : "memory");
          WAITV0;
          if (__all((f0 & f1 & f2) == 1)) break;
          __builtin_amdgcn_s_sleep(4);
        }
        __syncthreads();
        if (l < 32){                           // reload current-step gx (was not prefetched)
          const float* g0 = gx + ((size_t)(pb*512 + t))*TDK + dg;
          asm volatile("global_load_dword %0, %1, off sc0 sc1" : "=v"(xr) : "v"(g0)        : "memory");
          asm volatile("global_load_dword %0, %1, off sc0 sc1" : "=v"(xz) : "v"(g0 + 1024) : "memory");
          asm volatile("global_load_dword %0, %1, off sc0 sc1" : "=v"(xn) : "v"(g0 + 2048) : "memory");
        }
        WAITV0;
      }
      // poll slot t (issue polls FIRST, then gx(t+1): counted wait leaves only gx outstanding)
      uint4 rw[8];
      unsigned ok = 0;
      const unsigned tagv = (unsigned)(t + 1);
      const unsigned* qb = hw + ((size_t)t << 13) + (w << 8) + (l << 2);
      #pragma unroll
      for (int j = 0; j < 8; ++j)
        asm volatile("global_load_dwordx4 %0, %1, off sc0 sc1" : "=v"(rw[j]) : "v"(qb + (j << 10)) : "memory");
      const bool gxi = (((t+1) & 127) != 0) && (t+1 < 512);
      if (gxi && l < 32){
        const float* g0 = gx + ((size_t)(pb*512 + t + 1))*TDK + dg;
        asm volatile("global_load_dword %0, %1, off sc0 sc1" : "=v"(nxr) : "v"(g0)        : "memory");
        asm volatile("global_load_dword %0, %1, off sc0 sc1" : "=v"(nxz) : "v"(g0 + 1024) : "memory");
        asm volatile("global_load_dword %0, %1, off sc0 sc1" : "=v"(nxn) : "v"(g0 + 2048) : "memory");
      }
      if (gxi) { WAITV3; } else { WAITV0; }
      #pragma unroll
      for (int j = 0; j < 8; ++j){
        unsigned m = (rw[j].x ^ tagv) | (rw[j].y ^ tagv) | (rw[j].z ^ tagv) | (rw[j].w ^ tagv);
        if ((m & 0xFFFFu) == 0u) ok |= (1u << j);
      }
      while (!__all(ok == 0xFFu)){
        #pragma unroll
        for (int j = 0; j < 8; ++j){
          if (!(ok & (1u << j)))
            asm volatile("global_load_dwordx4 %0, %1, off sc0 sc1" : "=v"(rw[j]) : "v"(qb + (j << 10)) : "memory");
        }
        WAITV0;
        #pragma unroll
        for (int j = 0; j < 8; ++j){
          if (!(ok & (1u << j))){
            unsigned m = (rw[j].x ^ tagv) | (rw[j].y ^ tagv) | (rw[j].z ^ tagv) | (rw[j].w ^ tagv);
            if ((m & 0xFFFFu) == 0u) ok |= (1u << j);
          }
        }
      }
      // strip tags -> wave-private LDS
      #pragma unroll
      for (int j = 0; j < 8; ++j){
        unsigned d0 = __builtin_amdgcn_perm(rw[j].y, rw[j].x, 0x07060302u);
        unsigned d1 = __builtin_amdgcn_perm(rw[j].w, rw[j].z, 0x07060302u);
        union { unsigned u[2]; unsigned long long ull; } cv; cv.u[0]=d0; cv.u[1]=d1;
        *(unsigned long long*)&Hld[w*8 + j][l<<2] = cv.ull;
      }
      f32x4 ac0 = {0.f,0.f,0.f,0.f}, ac1 = {0.f,0.f,0.f,0.f}, ac2 = {0.f,0.f,0.f,0.f};
      #pragma unroll
      for (int s = 0; s < 8; ++s){
        bf16x8 af = *(const bf16x8*)&Hld[w*8 + (ar & 7)][(s << 5) + kg];
        ac0 = __builtin_amdgcn_mfma_f32_16x16x32_bf16(af, Bf[0][s], ac0, 0, 0, 0);
        ac1 = __builtin_amdgcn_mfma_f32_16x16x32_bf16(af, Bf[1][s], ac1, 0, 0, 0);
        ac2 = __builtin_amdgcn_mfma_f32_16x16x32_bf16(af, Bf[2][s], ac2, 0, 0, 0);
      }
      const int cur = t & 1;
      if (l < 32){
        *(f32x4*)(&Red[cur*1536 + (w*3+0)*128 + l*4]) = ac0;
        *(f32x4*)(&Red[cur*1536 + (w*3+1)*128 + l*4]) = ac1;
        *(f32x4*)(&Red[cur*1536 + (w*3+2)*128 + l*4]) = ac2;
      }
      __syncthreads();
      if (l < 32){
        const int idx = (((pb>>2)<<4) | pi)*4 + (pb & 3);
        const float* R = Red + cur*1536;
        float ghr = R[idx]       + R[384 + idx]  + R[768 + idx]  + R[1152 + idx];
        float ghz = R[128 + idx] + R[512 + idx]  + R[896 + idx]  + R[1280 + idx];
        float ghn = R[256 + idx] + R[640 + idx]  + R[1024 + idx] + R[1408 + idx];
        float r  = sigmoidf_(xr + ghr + bhr);
        float z  = sigmoidf_(xz + ghz + bhz);
        float nn = tanhf(xn + r*(ghn + bhn));
        hp = (1.f - z)*nn + z*hp;
        hacc += hp;
        unsigned word = (((unsigned)f2bf(hp)) << 16) | (unsigned)(t + 2);
        unsigned* hdst = hw + ((size_t)(t+1) << 13) + (pb << 10) + dg;
        asm volatile("global_store_dword %0, %1, off sc0 sc1" :: "v"(hdst), "v"(word) : "memory");
      }
      if (c == 0 && tid == 0){                  // watermark: all WGs completed step t-? see tokfeat gate
        asm volatile("global_store_dword %0, %1, off sc0 sc1" :: "v"(wm), "v"(t) : "memory");
      }
      if (gxi && l < 32){ xr = nxr; xz = nxz; xn = nxn; }
    }
    if (l < 32) hsum[(pb << 10) + dg] = hacc;   // plain store; consumed post-dispatch
    return;
  }

  // ---------------- helper path ----------------
  const int hid = blockIdx.x - NGRU;            // 0..191
  ushort* As = (ushort*)smem;
  ushort* Bs = As + 8192;

  // phase 1: gx GEMM tiles in t-priority order (wv = t-block)
  {
    const int bb = hid / 24, ni = hid % 24;
    const int wr_ = w >> 1, wc_ = w & 1;
    const int lr = l >> 3, lcol = (l & 7) << 3;
    for (int wv = 0; wv < 4; ++wv){
      const int mi = bb*4 + wv;
      f32x4 acc[4][4] = {};
      for (int k0 = 0; k0 < 1024; k0 += 64){
        __syncthreads();
        #pragma unroll
        for (int g = 0; g < 4; ++g){
          const int chunk = (g<<2) + w;
          const int row = (chunk<<3) + lr;
          gload_lds16(xmb + (size_t)(mi*128 + row)*1024 + k0 + lcol, &As[chunk<<9]);
          gload_lds16(wihb + (size_t)(ni*128 + row)*1024 + k0 + lcol, &Bs[chunk<<9]);
        }
        __syncthreads();
        #pragma unroll
        for (int kk = 0; kk < 2; ++kk){
          bf16x8 af[4], bfr[4];
          #pragma unroll
          for (int m=0;m<4;++m) af[m]  = *(const bf16x8*)&As[(wr_*64 + m*16 + (l&15))*64 + kk*32 + ((l>>4)<<3)];
          #pragma unroll
          for (int n=0;n<4;++n) bfr[n] = *(const bf16x8*)&Bs[(wc_*64 + n*16 + (l&15))*64 + kk*32 + ((l>>4)<<3)];
          #pragma unroll
          for (int m=0;m<4;++m)
            #pragma unroll
            for (int n=0;n<4;++n)
              acc[m][n] = __builtin_amdgcn_mfma_f32_16x16x32_bf16(af[m], bfr[n], acc[m][n], 0, 0, 0);
        }
      }
      const int row0 = mi*128 + wr_*64 + ((l>>4)<<2);
      const int col0 = ni*128 + wc_*64 + (l&15);
      #pragma unroll
      for (int m=0;m<4;++m){
        #pragma unroll
        for (int n=0;n<4;++n){
          f32x4 a = acc[m][n];
          int col = col0 + n*16;
          float bi = ebih[col];
          #pragma unroll
          for (int q=0;q<4;++q){
            int row = row0 + m*16 + q;
            float val = a[q] + bi;
            float* p = gx + (size_t)row*TDK + col;
            asm volatile("global_store_dword %0, %1, off sc0 sc1" :: "v"(p), "v"(val) : "memory");
          }
        }
      }
      WAITV0;
      __syncthreads();
      if (tid == 0){
        int one = 1;
        const int* fp = done + wv*192 + hid;
        asm volatile("global_store_dword %0, %1, off sc0 sc1" :: "v"(fp), "v"(one) : "memory");
      }
      __syncthreads();
    }
  }
  // phase 2: w1b (zero-padded) and w2t conversions (plain stores; consumed post-dispatch)
  for (int row = hid; row < 8192; row += NHELP){
    const float* src = opW1 + (size_t)row*I_;
    ushort* dst = w1b + (size_t)row*KP_;
    for (int cc = tid; cc < KP_; cc += 256){
      float v = (cc < I_) ? src[cc] : 0.f;
      dst[cc] = f2bf(v);
    }
  }
  for (int blk = hid; blk < 8192; blk += NHELP){
    const int v = blk >> 10, d = blk & 1023;
    const float4* src = (const float4*)(opW2 + ((size_t)(v*1024 + d))*1024);
    ushort* dst = w2t + (size_t)d*8192 + v*1024;
    float4 u = src[tid];
    ushort4 h; h.x=f2bf(u.x); h.y=f2bf(u.y); h.z=f2bf(u.z); h.w=f2bf(u.w);
    ((ushort4*)dst)[tid] = h;
  }
  // phase 3: xsum (WGs 64..95): xsum[o] = sum_t xm[b][t][d]
  if (hid < 32){
    const int o = hid*256 + tid;                // 0..8191
    const int b = o >> 10, d = o & 1023;
    float s = 0.f;
    for (int t = 0; t < 512; ++t) s += xm[((size_t)(b*512 + t) << 10) + d];
    xsum[o] = s;
  }
  // phase 4: tokfeat per token, gated by watermark + tag-check
  {
    float* xe = (float*)smem;
    for (int idx = hid; idx < 4096; idx += NHELP){
      const int t = idx >> 3, b = idx & 7;
      const int tok = b*512 + t;
      const int need = (t+1 < 511) ? (t+1) : 511;
      if (tid == 0){
        int wmv;
        while (true){
          asm volatile("global_load_dword %0, %1, off sc0 sc1" : "=v"(wmv) : "v"(wm) : "memory");
          asm volatile("s_waitcnt vmcnt(0)" ::: "memory");
          if (wmv >= need) break;
          __builtin_amdgcn_s_sleep(64);
        }
      }
      __syncthreads();
      const unsigned tagv = (unsigned)(t + 2);
      const unsigned* src = hw + ((size_t)(t+1) << 13) + (b << 10) + (tid << 2);
      uint4 hv;
      while (true){
        asm volatile("global_load_dwordx4 %0, %1, off sc0 sc1" : "=v"(hv) : "v"(src) : "memory");
        WAITV0;
        unsigned m = (hv.x ^ tagv) | (hv.y ^ tagv) | (hv.z ^ tagv) | (hv.w ^ tagv);
        if (__syncthreads_and((int)((m & 0xFFFFu) == 0u))) break;
        __builtin_amdgcn_s_sleep(16);
      }
      float4 xv = ((const float4*)(xm + (size_t)tok*1024))[tid];
      float4 ev;
      ev.x = bf2f((ushort)(hv.x >> 16)) + xv.x;
      ev.y = bf2f((ushort)(hv.y >> 16)) + xv.y;
      ev.z = bf2f((ushort)(hv.z >> 16)) + xv.z;
      ev.w = bf2f((ushort)(hv.w >> 16)) + xv.w;
      *(float4*)&xe[tid*4] = ev;
      ushort4 eb; eb.x=f2bf(ev.x); eb.y=f2bf(ev.y); eb.z=f2bf(ev.z); eb.w=f2bf(ev.w);
      *(ushort4*)&tf[(size_t)tok*KP_ + tid*4] = eb;
      __syncthreads();
      const int j = tid >> 5, ln = tid & 31;
      const float* Wr = (j < 6) ? (ttW + j*1024) : (polW + (j-6)*1024);
      float acc = 0.f;
      for (int k = ln; k < 1024; k += 32) acc += xe[k]*Wr[k];
      #pragma unroll
      for (int m=16; m>=1; m>>=1) acc += __shfl_xor(acc, m, 32);
      if (ln == 0){
        float val = acc + ((j<6)? ttb[j] : polb[j-6]);
        ttpol[(size_t)tok*8 + j] = val;
        tf[(size_t)tok*KP_ + 1024 + j] = f2bf(val);
      }
      if (tid < 56) tf[(size_t)tok*KP_ + 1032 + tid] = 0;
      __syncthreads();
    }
  }
}

__global__ __launch_bounds__(64) void k_csum(const float* __restrict__ ttpol, float* __restrict__ csum){
  const int b = threadIdx.x >> 3, j = threadIdx.x & 7;
  float s = 0.f;
  for (int t=0; t<512; ++t) s += ttpol[((size_t)(b*512+t)<<3) + j];
  csum[threadIdx.x] = s * (1.f/512.f);
}

// pg_h0 = context @ c2h_W^T + c2h_b   (pooled = (hsum+xsum)/512)
__global__ __launch_bounds__(256) void k_ctx(const float* __restrict__ hsum, const float* __restrict__ xsum,
                                             const float* __restrict__ csum,
                                             const float* __restrict__ c2hW, const float* __restrict__ c2hb,
                                             float* __restrict__ pgh0){
  const int i = blockIdx.x*256 + threadIdx.x;   // 8192
  const int b = i >> 10, d = i & 1023;
  const float* wr = c2hW + (size_t)d*I_;
  const float* hs = hsum + (b<<10);
  const float* xs = xsum + (b<<10);
  float s = 0.f;
  for (int k=0; k<1024; ++k) s += (hs[k]+xs[k])*wr[k];
  float acc = c2hb[d] + s*(1.f/512.f);
  #pragma unroll
  for (int k=0; k<8; ++k) acc += csum[b*8+k]*wr[1024+k];
  pgh0[i] = acc;
}

// one PG GRU step (rnn_in = 0 so gx = pg_bih)
__global__ __launch_bounds__(256) void k_pg(const float* __restrict__ whh, const float* __restrict__ bih,
                                            const float* __restrict__ bhh, const float* __restrict__ hin,
                                            float* __restrict__ hout){
  __shared__ float sh[8][1024];
  const int tid = threadIdx.x;
  for (int f = tid; f < 2048; f += 256) ((float4*)&sh[0][0])[f] = ((const float4*)hin)[f];
  __syncthreads();
  const int d = blockIdx.x*8 + (tid>>5), ln = tid & 31;
  const float* wr = whh + (size_t)d*1024;
  const float* wz = whh + (size_t)(1024+d)*1024;
  const float* wn = whh + (size_t)(2048+d)*1024;
  float ar[8]={0,0,0,0,0,0,0,0}, az[8]={0,0,0,0,0,0,0,0}, an[8]={0,0,0,0,0,0,0,0};
  for (int k = ln; k < 1024; k += 32){
    float r_=wr[k], z_=wz[k], n_=wn[k];
    #pragma unroll
    for (int b=0;b<8;++b){ float h = sh[b][k]; ar[b]+=h*r_; az[b]+=h*z_; an[b]+=h*n_; }
  }
  #pragma unroll
  for (int m=16; m>=1; m>>=1){
    #pragma unroll
    for (int b=0;b<8;++b){ ar[b]+=__shfl_xor(ar[b],m,32); az[b]+=__shfl_xor(az[b],m,32); an[b]+=__shfl_xor(an[b],m,32); }
  }
  if (ln == 0){
    float xr=bih[d], xz=bih[1024+d], xn=bih[2048+d];
    float br=bhh[d], bz=bhh[1024+d], bn=bhh[2048+d];
    #pragma unroll
    for (int b=0;b<8;++b){
      float r = sigmoidf_(xr + ar[b] + br);
      float z = sigmoidf_(xz + az[b] + bz);
      float nn = tanhf(xn + r*(an[b] + bn));
      hout[(b<<10)+d] = (1.f - z)*nn + z*sh[b][d];
    }
  }
}

// program logits + softmax + mean over L -> w[b][v]
__global__ __launch_bounds__(256) void k_wlogits(const float* __restrict__ pgh, const float* __restrict__ prjW,
                                                 const float* __restrict__ prjb, float* __restrict__ plog,
                                                 float* __restrict__ wv){
  __shared__ float lg[256];
  __shared__ float sm[256];
  const int tid = threadIdx.x;
  const int b = tid>>5, li = (tid>>3)&3, v = tid&7;
  const float* h = pgh + (size_t)(li+1)*8192 + (b<<10);
  const float* pw = prjW + (v<<10);
  float acc = prjb[v];
  for (int k=0;k<1024;++k) acc += h[k]*pw[k];
  lg[tid] = acc;
  plog[tid] = acc;
  __syncthreads();
  if (tid < 32){
    const int bb = tid>>2, ll = tid&3;
    const float* row = &lg[bb*32 + ll*8];
    float mx = row[0];
    #pragma unroll
    for (int u=1;u<8;++u) mx = fmaxf(mx, row[u]);
    float e[8], s=0.f;
    #pragma unroll
    for (int u=0;u<8;++u){ e[u]=__expf(row[u]-mx); s+=e[u]; }
    #pragma unroll
    for (int u=0;u<8;++u) sm[(bb*4+ll)*8+u] = e[u]/s;
  }
  __syncthreads();
  if (tid < 64){
    const int bb = tid>>3, u = tid&7;
    float s = sm[(bb*4+0)*8+u] + sm[(bb*4+1)*8+u] + sm[(bb*4+2)*8+u] + sm[(bb*4+3)*8+u];
    wv[bb*8+u] = 0.25f*s;
  }
}

__global__ __launch_bounds__(256) void k_obias(const float* __restrict__ wv, const float* __restrict__ opb2,
                                               float* __restrict__ obias){
  const int i = blockIdx.x*256 + threadIdx.x;   // 8192
  const int b = i>>10, d = i&1023;
  float s = 0.f;
  #pragma unroll
  for (int v=0; v<8; ++v) s += wv[b*8+v]*opb2[(v<<10)+d];
  obias[i] = s;
}

// pooled2 = [max_t out | mean_t out]
__global__ __launch_bounds__(128) void k_pool2(const float* __restrict__ outb, float* __restrict__ pooled2){
  const int b = blockIdx.x >> 3;
  const int col = ((blockIdx.x & 7) << 7) + threadIdx.x;
  float mx = -3.4e38f, sm = 0.f;
  for (int t=0; t<512; ++t){
    float v = outb[((size_t)(b*512+t)<<10) + col];
    mx = fmaxf(mx, v); sm += v;
  }
  pooled2[((size_t)b<<11) + col] = mx;
  pooled2[((size_t)b<<11) + 1024 + col] = sm*(1.f/512.f);
}

// z = pooled2 @ out_W^T + out_b  -> d_out[0..8191]
__global__ __launch_bounds__(256) void k_z(const float* __restrict__ pooled2, const float* __restrict__ outW,
                                           const float* __restrict__ outBias, float* __restrict__ dout){
  __shared__ float p2[2048];
  const int o = blockIdx.x << 3;
  const int b = o >> 10, dbase = o & 1023;
  for (int f = threadIdx.x; f < 512; f += 256)
    ((float4*)p2)[f] = ((const float4*)(pooled2 + ((size_t)b<<11)))[f];
  __syncthreads();
  const int g = threadIdx.x >> 5, ln = threadIdx.x & 31;
  const int d = dbase + g;
  const float* wr = outW + ((size_t)d << 11);
  float acc = 0.f;
  for (int k = ln; k < 2048; k += 32) acc += p2[k]*wr[k];
  #pragma unroll
  for (int m=16; m>=1; m>>=1) acc += __shfl_xor(acc, m, 32);
  if (ln == 0) dout[(b<<10) + d] = acc + outBias[d];
}

// reuse + contrastive losses (exact f32)
__global__ __launch_bounds__(64) void k_losses(const float* __restrict__ p2g, const float* __restrict__ plog,
                                               float* __restrict__ dout){
  __shared__ float p2n[8], sq[8], pn[8];
  const int l = threadIdx.x;
  { const int b=l>>3, p=l&7; float s=0.f;
    const float* row = p2g + ((size_t)b<<11) + (p<<8);
    for (int k=0;k<256;++k){ float v=row[k]; s += v*v; }
    s += __shfl_xor(s,4,8); s += __shfl_xor(s,2,8); s += __shfl_xor(s,1,8);
    if (p==0) p2n[b] = fmaxf(sqrtf(s), 1e-12f);
  }
  if (l < 8){
    float s=0.f;
    #pragma unroll
    for (int k=0;k<32;++k){ float v=plog[l*32+k]; s+=v*v; }
    sq[l]=s; pn[l]=fmaxf(sqrtf(s),1e-12f);
  }
  __syncthreads();
  const int i=l>>3, j=l&7;
  const float* ri = p2g + ((size_t)i<<11);
  const float* rj = p2g + ((size_t)j<<11);
  float dot=0.f; for (int k=0;k<2048;++k) dot += ri[k]*rj[k];
  float sim = dot/(p2n[i]*p2n[j]);
  float pd=0.f;
  #pragma unroll
  for (int k=0;k<32;++k) pd += plog[i*32+k]*plog[j*32+k];
  float d2 = fmaxf(sq[i]+sq[j]-2.f*pd, 0.f);
  float dist = (d2>0.f)? sqrtf(d2) : 0.f;
  float psim = pd/(pn[i]*pn[j]);
  float pos = (sim>0.7f)?1.f:0.f, neg = (sim<0.7f)?1.f:0.f;
  float rs = sim*dist, ps=(1.f-psim)*pos, ns=fmaxf(psim-0.5f,0.f)*neg, pc=pos, nc=neg;
  #pragma unroll
  for (int m=32; m>=1; m>>=1){
    rs+=__shfl_xor(rs,m); ps+=__shfl_xor(ps,m); ns+=__shfl_xor(ns,m);
    pc+=__shfl_xor(pc,m); nc+=__shfl_xor(nc,m);
  }
  if (l==0){ dout[8192]=rs*(1.f/64.f); dout[8193]=(ps+ns)/(pc+nc+1e-6f); }
}

// ============================ host ============================
extern "C" void kernel_launch(void* const* d_in, const int* in_sizes, int n_in,
                              void* d_out, int out_size, void* d_ws, size_t ws_size,
                              hipStream_t stream) {
  (void)in_sizes; (void)n_in; (void)out_size; (void)ws_size;
  const float* x     = (const float*)d_in[0];
  const float* amask = (const float*)d_in[1];
  const float* eWih  = (const float*)d_in[2];
  const float* eWhh  = (const float*)d_in[3];
  const float* ebih  = (const float*)d_in[4];
  const float* ebhh  = (const float*)d_in[5];
  const float* ttW   = (const float*)d_in[6];
  const float* ttb   = (const float*)d_in[7];
  const float* polW  = (const float*)d_in[8];
  const float* polb  = (const float*)d_in[9];
  const float* c2hW  = (const float*)d_in[10];
  const float* c2hb  = (const float*)d_in[11];
  const float* pgWhh = (const float*)d_in[13];
  const float* pgbih = (const float*)d_in[14];
  const float* pgbhh = (const float*)d_in[15];
  const float* prjW  = (const float*)d_in[16];
  const float* prjb  = (const float*)d_in[17];
  const float* opW1  = (const float*)d_in[18];
  const float* opb1  = (const float*)d_in[19];
  const float* opW2  = (const float*)d_in[20];
  const float* opb2  = (const float*)d_in[21];
  const float* outW  = (const float*)d_in[22];
  const float* outB  = (const float*)d_in[23];
  float* dout = (float*)d_out;

  char* ws = (char*)d_ws;
  size_t off = 0;
  auto alloc = [&](size_t bytes)->void*{ void* p = ws + off; off += (bytes + 255) & ~(size_t)255; return p; };
  // R region (64MB): xm (16MB) + gx (48MB), later reused as h1g (4096 x 8192 bf16 = 64MB)
  char*     R       = (char*)   alloc(64ULL*1024*1024);
  float*    xm      = (float*)  R;
  float*    gx      = (float*) (R + 16ULL*1024*1024);
  ushort*   h1g     = (ushort*) R;
  ushort*   xmb     = (ushort*)  alloc(4096ULL*1024*2);
  ushort*   wihb    = (ushort*)  alloc(3072ULL*1024*2);
  unsigned* hw      = (unsigned*)alloc(513ULL*8192*4);
  float*    ttpol   = (float*)   alloc(4096ULL*8*4);
  ushort*   tf      = (ushort*)  alloc(4096ULL*KP_*2);
  ushort*   w1b     = (ushort*)  alloc(8ULL*1024*KP_*2);
  ushort*   w2t     = (ushort*)  alloc(1024ULL*8192*2);
  float*    outbuf  = (float*)   alloc(4096ULL*1024*4);
  float*    hsum    = (float*)   alloc(8192*4);
  float*    xsum    = (float*)   alloc(8192*4);
  float*    csum    = (float*)   alloc(64*4);
  float*    pgh     = (float*)   alloc(5ULL*8192*4);
  float*    plog    = (float*)   alloc(256*4);
  float*    wv      = (float*)   alloc(64*4);
  float*    obias   = (float*)   alloc(8192*4);
  float*    pooled2 = (float*)   alloc(16384*4);
  int*      ctrl    = (int*)     alloc(4096);
  int*      done    = ctrl;                     // [4*192]
  int*      wm      = ctrl + 896;               // separate line

  // control init + exchange-buffer init
  hipMemsetAsync(done, 0, 4*192*4, stream);
  hipMemsetAsync(wm, 0xFF, 4, stream);          // wm = -1
  k_hinit<<<32, 256, 0, stream>>>(hw);          // slot 0: value 0, tag 1
  k_prep<<<4096, 256, 0, stream>>>(x, amask, xm, xmb);
  k_cvt<<<3072, 256, 0, stream>>>(eWih, wihb, 3072*1024/4);

  // MEGA: recurrence + gx GEMM + weight conversions + xsum + tokfeat
  k_mega<<<256, 256, 0, stream>>>(eWhh, ebhh, xmb, wihb, ebih, gx, hw, xm,
                                  ttW, ttb, polW, polb, tf, ttpol,
                                  opW1, w1b, opW2, w2t, hsum, xsum, done, wm);

  // reductions + program generator
  k_csum<<<1, 64, 0, stream>>>(ttpol, csum);
  k_ctx<<<32, 256, 0, stream>>>(hsum, xsum, csum, c2hW, c2hb, pgh);
  for (int t = 0; t < 4; ++t)
    k_pg<<<128, 256, 0, stream>>>(pgWhh, pgbih, pgbhh, pgh + (size_t)t*8192, pgh + (size_t)(t+1)*8192);
  k_wlogits<<<1, 256, 0, stream>>>(pgh, prjW, prjb, plog, wv);
  k_obias<<<32, 256, 0, stream>>>(wv, opb2, obias);

  // op library fused: h1 (one dispatch, N=8192 over v) then out (one dispatch, K=8192 over v)
  { EpiArgs e{}; e.outh = h1g; e.bias = opb1; e.wvp = wv; e.ldc = 8192;
    k_gemm<1,false><<<dim3(32,64), 256, 0, stream>>>(tf, w1b, KP_, KP_, KP_, e); }
  { EpiArgs e{}; e.outf = outbuf; e.obias = obias; e.ldc = 1024;
    k_gemm<2,true><<<dim3(32,8), 256, 0, stream>>>(h1g, w2t, 8192, 8192, 8192, e); }

  // pooling + z + losses
  k_pool2<<<64, 128, 0, stream>>>(outbuf, pooled2);
  k_z<<<1024, 256, 0, stream>>>(pooled2, outW, outB, dout);
  k_losses<<<1, 64, 0, stream>>>(pooled2, plog, dout);
}